// Round 7
// baseline (1658.984 us; speedup 1.0000x reference)
//
#include <hip/hip_runtime.h>
#include <hip/hip_bf16.h>
#include <math.h>

#define N_NODES 50000
#define N_EDGES 600000
#define DIM 128
#define N_REL 8
#define N_BASES 8
#define N_GRAPHS 256
#define NB 16                 // nodes per block (50000 = 3125*16 exact)
#define NBLK (N_NODES / NB)   // 3125
#define KDIM 1024             // relation-stacked K = 8*128

typedef __attribute__((ext_vector_type(8))) short short8;
typedef __attribute__((ext_vector_type(4))) float floatx4;
typedef __attribute__((ext_vector_type(4))) float f32x4;
typedef unsigned int uint;
typedef unsigned short ushort;

static __device__ __forceinline__ int lower_bound_i(const int* a, int n, int v) {
    int lo = 0, hi = n;
    while (lo < hi) { int mid = (lo + hi) >> 1; if (a[mid] < v) lo = mid + 1; else hi = mid; }
    return lo;
}

// RNE float->bf16 split: hiword = bf16(x)|bf16(y)<<16 ; loword = bf16(x-hi)|bf16(y-hi)<<16
static __device__ __forceinline__ uint2 split2(float x, float y) {
    uint ux = __float_as_uint(x);
    uint hx = (ux + 0x7FFFu + ((ux >> 16) & 1u)) & 0xFFFF0000u;
    float rx = x - __uint_as_float(hx);
    uint urx = __float_as_uint(rx);
    uint lx = (urx + 0x7FFFu + ((urx >> 16) & 1u)) >> 16;
    uint uy = __float_as_uint(y);
    uint hy = (uy + 0x7FFFu + ((uy >> 16) & 1u)) & 0xFFFF0000u;
    float ry = y - __uint_as_float(hy);
    uint ury = __float_as_uint(ry);
    uint ly = (ury + 0x7FFFu + ((ury >> 16) & 1u)) >> 16;
    return make_uint2((hx >> 16) | (hy & 0xFFFF0000u), lx | (ly << 16));
}

__global__ void k_count(const int* __restrict__ dst, int* __restrict__ counts, int e) {
    int i = blockIdx.x * blockDim.x + threadIdx.x;
    if (i < e) atomicAdd(&counts[dst[i] >> 4], 1);
}

// exclusive scan over per-block counts (NBLK=3125), single 1024-thread block
__global__ __launch_bounds__(1024) void k_scan_small(const int* __restrict__ counts,
                                                     int* __restrict__ boff,
                                                     int* __restrict__ cursor) {
    const int t = threadIdx.x;
    int c[4]; int s = 0;
#pragma unroll
    for (int j = 0; j < 4; j++) {
        int idx = t * 4 + j;
        c[j] = (idx < NBLK) ? counts[idx] : 0;
        s += c[j];
    }
    __shared__ int sl[1024];
    sl[t] = s;
    __syncthreads();
    for (int off = 1; off < 1024; off <<= 1) {
        int v = (t >= off) ? sl[t - off] : 0;
        __syncthreads();
        sl[t] += v;
        __syncthreads();
    }
    int run = sl[t] - s;
#pragma unroll
    for (int j = 0; j < 4; j++) {
        int idx = t * 4 + j;
        if (idx < NBLK) { boff[idx] = run; cursor[idx] = run; run += c[j]; }
    }
    if (t == 1023) boff[NBLK] = sl[1023];
}

// scatter edges grouped by dst-block; pack src(16b) | etype(3b @16) | dst_local(4b @19)
__global__ void k_fill(const int* __restrict__ src, const int* __restrict__ dst,
                       const int* __restrict__ etype, int* cursor,
                       int* __restrict__ edges, int e) {
    int i = blockIdx.x * blockDim.x + threadIdx.x;
    if (i < e) {
        int d = dst[i];
        int pos = atomicAdd(&cursor[d >> 4], 1);
        edges[pos] = src[i] | (etype[i] << 16) | ((d & 15) << 19);
    }
}

// W[k=r*128+dk][col] = sum_b comp[r,b]*bases[b][dk][col], packed bf16 hi/lo
// into MFMA-B-fragment order [kt:32][col:128][kk:32] (read-coalesced mapping).
__global__ void k_packW(const float* __restrict__ bases, const float* __restrict__ comp,
                        ushort* __restrict__ Whi, ushort* __restrict__ Wlo) {
    int id = blockIdx.x * blockDim.x + threadIdx.x;  // 131072
    int nn = id & 127, k = id >> 7;
    int r = k >> 7, dk = k & 127;
    const float* cp = comp + r * 8;
    float v = 0.f;
#pragma unroll
    for (int b = 0; b < 8; b++) v = fmaf(cp[b], bases[((size_t)b * 128 + dk) * 128 + nn], v);
    uint u = __float_as_uint(v);
    uint hu = (u + 0x7FFFu + ((u >> 16) & 1u)) & 0xFFFF0000u;
    float rf = v - __uint_as_float(hu);
    uint ur = __float_as_uint(rf);
    uint lu = (ur + 0x7FFFu + ((ur >> 16) & 1u)) >> 16;
    int kt = k >> 5, kk = k & 31;
    int off = kt * 4096 + nn * 32 + kk;
    Whi[off] = (ushort)(hu >> 16);
    Wlo[off] = (ushort)lu;
}

// One RGCN layer, fused, 512 threads (8 waves):
//  phase 1: EDGE-CENTRIC relation-space aggregation. Half-wave h processes
//           edges E0+h+16i of the block's contiguous CSR range (perfect
//           balance). Per edge: 1x 16B x-row gather + 4x ds_add_f32 into fp32
//           LDS aggR[16 nodes][8 rel][128 dims] (64 KB). No per-edge comp FMA.
//  transform: in-place fp32 -> bf16 hi/lo MFMA A-fragment layout (register-
//           staged read-all/barrier/write-all; layout identical to R6).
//  phase 2: [16 x 1024] @ [1024 x 128] via mfma_f32_16x16x32_bf16, 3-term
//           split, B = relation-stacked W (comp folded in by k_packW).
//  GATE:    layer-3 epilogue computes gate[n] = h3[n,:].gw + gb (fuses k_gate).
//
// PITFALL (R3): never let per-call-rebuilt arrays (edges/boff) be loaded via
// provably wave-uniform addresses -> compiler s_load via scalar cache serves
// STALE data on graph replay. boff is read with a lane-divergent address +
// __shfl broadcast; edges[] indices derive from tid.
template <bool RELU, bool GATE>
__global__ __launch_bounds__(512, 4) void k_layer(
    const float* __restrict__ xin, float* __restrict__ hout,
    const int* __restrict__ edges, const int* __restrict__ boff,
    const ushort* __restrict__ Whi, const ushort* __restrict__ Wlo,
    const float* __restrict__ bias,
    const float* __restrict__ gw, const float* __restrict__ gb,
    float* __restrict__ gate) {
    __shared__ uint ldsU[NB * KDIM];  // 64 KiB, multi-purpose
    __shared__ float sgate[NB];
    float* sAgg = (float*)ldsU;
    ushort* sHi = (ushort*)ldsU;            // first 32 KiB (after transform)
    ushort* sLo = (ushort*)(ldsU + 8192);   // second 32 KiB
    const int tid = threadIdx.x;
    const int lane = tid & 63;

    // zero the fp32 accumulator
#pragma unroll
    for (int rr = 0; rr < 8; ++rr)
        *(float4*)(sAgg + rr * 2048 + tid * 4) = make_float4(0.f, 0.f, 0.f, 0.f);
    if (GATE && tid < NB) sgate[tid] = 0.f;
    __syncthreads();

    // ---- phase 1: edge-centric relation-space aggregation ----
    {
        const int vb = boff[blockIdx.x + (lane & 1)];  // lane-divergent -> vector load
        const int E0 = __shfl(vb, 0), E1 = __shfl(vb, 1);
        const int h = tid >> 5, l5 = tid & 31;
        const int d4 = l5 * 4;
        int e0 = E0 + h;
        int pk0 = 0, pk1 = 0;
        f32x4 v0 = (f32x4)0.f;
        if (e0 < E1) pk0 = edges[e0];
        const int e1i = e0 + 16;
        if (e1i < E1) pk1 = edges[e1i];
        if (e0 < E1) v0 = *(const f32x4*)(xin + (size_t)(pk0 & 0xFFFF) * DIM + d4);
        int e1 = e1i;
        while (e0 < E1) {
            const int e2 = e1 + 16;
            int pk2 = 0;
            if (e2 < E1) pk2 = edges[e2];          // desc 2 ahead
            f32x4 v1 = (f32x4)0.f;
            if (e1 < E1) v1 = *(const f32x4*)(xin + (size_t)(pk1 & 0xFFFF) * DIM + d4);  // gather 1 ahead
            // consume current edge
            {
                const int node = (pk0 >> 19) & 15;
                const int r = (pk0 >> 16) & 7;
                float* bp = sAgg + node * 1024 + r * 128 + d4;
                atomicAdd(bp + 0, v0.x);
                atomicAdd(bp + 1, v0.y);
                atomicAdd(bp + 2, v0.z);
                atomicAdd(bp + 3, v0.w);
            }
            e0 = e1; pk0 = pk1; v0 = v1;
            e1 = e2; pk1 = pk2;
        }
    }
    __syncthreads();

    // ---- transform: fp32 aggR -> bf16 hi/lo A-fragments, in place ----
    {
        uint vals[32];
#pragma unroll
        for (int rd = 0; rd < 16; ++rd) {
            const uint2 u = *(const uint2*)(ldsU + rd * 1024 + tid * 2);
            vals[rd * 2] = u.x; vals[rd * 2 + 1] = u.y;
        }
        __syncthreads();  // all reads done before any write (in-place safety)
        const int kt = tid >> 4;            // k = tid*2
        const int q = (tid >> 2) & 3;
        const int j = (tid & 3) * 2;
        const int base_us = kt * 512 + q * 128 + j;  // + chunk_low*8
#pragma unroll
        for (int rd = 0; rd < 16; ++rd) {   // rd = node
            const int clow = (rd ^ q) ^ ((kt & 1) << 2);
            const int us = base_us + clow * 8;
            const uint2 p = split2(__uint_as_float(vals[rd * 2]),
                                   __uint_as_float(vals[rd * 2 + 1]));
            *(uint*)(sHi + us) = p.x;
            *(uint*)(sLo + us) = p.y;
        }
    }
    __syncthreads();

    // ---- phase 2: MFMA GEMM, each of 8 waves owns one 16-col strip ----
    const int w = tid >> 6;
    const int q2 = lane >> 4, mm = lane & 15;
    const int a_even = (q2 * 16 + (mm ^ q2)) * 8;        // kt even
    const int a_odd  = (q2 * 16 + ((mm ^ q2) ^ 4)) * 8;  // kt odd (parity swizzle)
    const int n0 = w * 16 + mm;
    const ushort* bph = Whi + n0 * 32 + q2 * 8;
    const ushort* bpl = Wlo + n0 * 32 + q2 * 8;
    floatx4 acc0 = {0.f, 0.f, 0.f, 0.f};
    for (int kt = 0; kt < 32; kt += 2) {
        {
            const short8 ah = *(const short8*)(sHi + kt * 512 + a_even);
            const short8 al = *(const short8*)(sLo + kt * 512 + a_even);
            const short8 bh = *(const short8*)(bph + kt * 4096);
            const short8 bl = *(const short8*)(bpl + kt * 4096);
            acc0 = __builtin_amdgcn_mfma_f32_16x16x32_bf16(ah, bh, acc0, 0, 0, 0);
            acc0 = __builtin_amdgcn_mfma_f32_16x16x32_bf16(ah, bl, acc0, 0, 0, 0);
            acc0 = __builtin_amdgcn_mfma_f32_16x16x32_bf16(al, bh, acc0, 0, 0, 0);
        }
        {
            const int kto = kt + 1;
            const short8 ah = *(const short8*)(sHi + kto * 512 + a_odd);
            const short8 al = *(const short8*)(sLo + kto * 512 + a_odd);
            const short8 bh = *(const short8*)(bph + kto * 4096);
            const short8 bl = *(const short8*)(bpl + kto * 4096);
            acc0 = __builtin_amdgcn_mfma_f32_16x16x32_bf16(ah, bh, acc0, 0, 0, 0);
            acc0 = __builtin_amdgcn_mfma_f32_16x16x32_bf16(ah, bl, acc0, 0, 0, 0);
            acc0 = __builtin_amdgcn_mfma_f32_16x16x32_bf16(al, bh, acc0, 0, 0, 0);
        }
    }
    const float b0 = bias[n0];
    float gp[4];
#pragma unroll
    for (int r = 0; r < 4; r++) {
        const int node = blockIdx.x * NB + q2 * 4 + r;  // C/D: row=(lane>>4)*4+reg, col=lane&15
        float v0 = acc0[r] + b0;
        if (RELU) v0 = fmaxf(v0, 0.f);
        hout[(size_t)node * DIM + n0] = v0;
        if (GATE) gp[r] = v0 * gw[n0];
    }
    if (GATE) {
#pragma unroll
        for (int r = 0; r < 4; r++) {
#pragma unroll
            for (int off = 1; off < 16; off <<= 1) gp[r] += __shfl_xor(gp[r], off, 16);
        }
        if ((lane & 15) == 0) {
#pragma unroll
            for (int r = 0; r < 4; r++) atomicAdd(&sgate[q2 * 4 + r], gp[r]);
        }
        __syncthreads();
        if (tid < NB) gate[blockIdx.x * NB + tid] = sgate[tid] + gb[0];
    }
}

// One block (256 threads) per graph: segment softmax + weighted readout + MLP head + sigmoid.
__global__ __launch_bounds__(256) void k_pool(
    const float* __restrict__ h3, const float* __restrict__ gate, const int* __restrict__ n2g,
    const float* __restrict__ fc1w, const float* __restrict__ fc1b,
    const float* __restrict__ fc2w, const float* __restrict__ fc2b,
    const float* __restrict__ fc3w, const float* __restrict__ fc3b,
    float* __restrict__ out, int N) {
    const int g = blockIdx.x;
    const int tid = threadIdx.x;
    __shared__ float sred[256];
    __shared__ float sr[128];
    __shared__ float sz1[100];
    __shared__ float sz2[64];
    __shared__ float sm, ssum;

    const int s = lower_bound_i(n2g, N, g);
    const int e = lower_bound_i(n2g, N, g + 1);

    float m = -3.4e38f;
    for (int n = s + tid; n < e; n += 256) m = fmaxf(m, gate[n]);
    sred[tid] = m;
    __syncthreads();
    for (int off = 128; off > 0; off >>= 1) {
        if (tid < off) sred[tid] = fmaxf(sred[tid], sred[tid + off]);
        __syncthreads();
    }
    if (tid == 0) sm = sred[0];
    __syncthreads();
    const float mm = sm;

    float sum = 0.f;
    for (int n = s + tid; n < e; n += 256) sum += expf(gate[n] - mm);
    sred[tid] = sum;
    __syncthreads();
    for (int off = 128; off > 0; off >>= 1) {
        if (tid < off) sred[tid] += sred[tid + off];
        __syncthreads();
    }
    if (tid == 0) ssum = sred[0];
    __syncthreads();
    const float inv = (e > s) ? 1.0f / ssum : 0.f;

    // weighted readout: col = tid&127, node stream split across two halves
    const int col = tid & 127;
    const int half = tid >> 7;
    float acc = 0.f;
    int n = s + half;
    for (; n + 2 < e; n += 4) {
        const float w0 = expf(gate[n] - mm);
        const float w1 = expf(gate[n + 2] - mm);
        const float a0 = h3[(size_t)n * DIM + col];
        const float a1 = h3[(size_t)(n + 2) * DIM + col];
        acc = fmaf(w0, a0, acc);
        acc = fmaf(w1, a1, acc);
    }
    for (; n < e; n += 2) {
        const float wgt = expf(gate[n] - mm);
        acc = fmaf(wgt, h3[(size_t)n * DIM + col], acc);
    }
    sred[tid] = acc;
    __syncthreads();
    if (tid < 128) sr[tid] = (sred[tid] + sred[tid + 128]) * inv;
    __syncthreads();

    if (tid < 100) {
        float t = fc1b[tid];
        for (int i = 0; i < 128; i++) t = fmaf(sr[i], fc1w[i * 100 + tid], t);
        sz1[tid] = fmaxf(t, 0.f);
    }
    __syncthreads();
    if (tid < 64) {
        float t = fc2b[tid];
        for (int i = 0; i < 100; i++) t = fmaf(sz1[i], fc2w[i * 64 + tid], t);
        sz2[tid] = fmaxf(t, 0.f);
    }
    __syncthreads();
    if (tid < 64) {
        float p = sz2[tid] * fc3w[tid];
#pragma unroll
        for (int off = 32; off > 0; off >>= 1) p += __shfl_down(p, off, 64);
        if (tid == 0) {
            const float z = p + fc3b[0];
            out[g] = 1.0f / (1.0f + expf(-z));
        }
    }
}

extern "C" void kernel_launch(void* const* d_in, const int* in_sizes, int n_in,
                              void* d_out, int out_size, void* d_ws, size_t ws_size,
                              hipStream_t stream) {
    (void)in_sizes; (void)n_in; (void)out_size; (void)ws_size;
    const float* features = (const float*)d_in[0];
    const int*   src      = (const int*)d_in[1];
    const int*   dst      = (const int*)d_in[2];
    const int*   etype    = (const int*)d_in[3];
    const int*   n2g      = (const int*)d_in[4];
    const float* bases1   = (const float*)d_in[5];
    const float* comp1    = (const float*)d_in[6];
    const float* bias1    = (const float*)d_in[7];
    const float* bases2   = (const float*)d_in[8];
    const float* comp2    = (const float*)d_in[9];
    const float* bias2    = (const float*)d_in[10];
    const float* bases3   = (const float*)d_in[11];
    const float* comp3    = (const float*)d_in[12];
    const float* bias3    = (const float*)d_in[13];
    const float* gate_w   = (const float*)d_in[14];
    const float* gate_b   = (const float*)d_in[15];
    const float* fc1w     = (const float*)d_in[16];
    const float* fc1b     = (const float*)d_in[17];
    const float* fc2w     = (const float*)d_in[18];
    const float* fc2b     = (const float*)d_in[19];
    const float* fc3w     = (const float*)d_in[20];
    const float* fc3b     = (const float*)d_in[21];
    float* out = (float*)d_out;

    char* w = (char*)d_ws;
    auto alloc = [&](size_t bytes) -> char* {
        char* p = w;
        w += (bytes + 255) & ~(size_t)255;
        return p;
    };
    int*    boff    = (int*)alloc((NBLK + 1) * sizeof(int));
    int*    counts  = (int*)alloc(NBLK * sizeof(int));
    int*    cursor  = (int*)alloc(NBLK * sizeof(int));
    int*    edges   = (int*)alloc(N_EDGES * sizeof(int));
    float*  hA      = (float*)alloc((size_t)N_NODES * DIM * sizeof(float));
    float*  hB      = (float*)alloc((size_t)N_NODES * DIM * sizeof(float));
    float*  gate    = (float*)alloc(N_NODES * sizeof(float));
    ushort* Whi1    = (ushort*)alloc((size_t)KDIM * DIM * sizeof(ushort));
    ushort* Wlo1    = (ushort*)alloc((size_t)KDIM * DIM * sizeof(ushort));
    ushort* Whi2    = (ushort*)alloc((size_t)KDIM * DIM * sizeof(ushort));
    ushort* Wlo2    = (ushort*)alloc((size_t)KDIM * DIM * sizeof(ushort));
    ushort* Whi3    = (ushort*)alloc((size_t)KDIM * DIM * sizeof(ushort));
    ushort* Wlo3    = (ushort*)alloc((size_t)KDIM * DIM * sizeof(ushort));

    // weight packing: W_r = comp@bases, bf16 hi/lo, MFMA fragment order
    k_packW<<<(KDIM * DIM) / 256, 256, 0, stream>>>(bases1, comp1, Whi1, Wlo1);
    k_packW<<<(KDIM * DIM) / 256, 256, 0, stream>>>(bases2, comp2, Whi2, Wlo2);
    k_packW<<<(KDIM * DIM) / 256, 256, 0, stream>>>(bases3, comp3, Whi3, Wlo3);

    // per-block CSR (rebuilt every call)
    hipMemsetAsync(counts, 0, NBLK * sizeof(int), stream);
    k_count<<<(N_EDGES + 255) / 256, 256, 0, stream>>>(dst, counts, N_EDGES);
    k_scan_small<<<1, 1024, 0, stream>>>(counts, boff, cursor);
    k_fill<<<(N_EDGES + 255) / 256, 256, 0, stream>>>(src, dst, etype, cursor, edges, N_EDGES);

    // 3 RGCN layers (edge-centric LDS-atomic aggregation + fused MFMA GEMM)
    k_layer<true, false><<<NBLK, 512, 0, stream>>>(features, hA, edges, boff, Whi1, Wlo1, bias1,
                                                   gate_w, gate_b, gate);
    k_layer<true, false><<<NBLK, 512, 0, stream>>>(hA, hB, edges, boff, Whi2, Wlo2, bias2,
                                                   gate_w, gate_b, gate);
    k_layer<false, true><<<NBLK, 512, 0, stream>>>(hB, hA, edges, boff, Whi3, Wlo3, bias3,
                                                   gate_w, gate_b, gate);

    // pooling + MLP head (gate already computed in layer 3)
    k_pool<<<N_GRAPHS, 256, 0, stream>>>(hA, gate, n2g, fc1w, fc1b, fc2w, fc2b, fc3w, fc3b, out, N_NODES);
}

// Round 8
// 624.149 us; speedup vs baseline: 2.6580x; 2.6580x over previous
//
#include <hip/hip_runtime.h>
#include <hip/hip_bf16.h>
#include <math.h>

#define N_NODES 50000
#define N_EDGES 600000
#define DIM 128
#define N_REL 8
#define N_BASES 8
#define N_GRAPHS 256
#define NB 16                 // nodes per block in layer kernel (50000 = 3125*16 exact)
#define KDIM (N_BASES * DIM)  // 1024
#define SEG 1024
#define NSEG 49               // ceil(50000/1024); NSEG*SEG = 50176

typedef __attribute__((ext_vector_type(8))) short short8;
typedef __attribute__((ext_vector_type(4))) float floatx4;
typedef __attribute__((ext_vector_type(4))) float f32x4;
typedef unsigned int uint;
typedef unsigned short ushort;

static __device__ __forceinline__ int lower_bound_i(const int* a, int n, int v) {
    int lo = 0, hi = n;
    while (lo < hi) { int mid = (lo + hi) >> 1; if (a[mid] < v) lo = mid + 1; else hi = mid; }
    return lo;
}

// RNE float->bf16 split: hiword = bf16(x)|bf16(y)<<16 ; loword = bf16(x-hi)|bf16(y-hi)<<16
static __device__ __forceinline__ uint2 split2(float x, float y) {
    uint ux = __float_as_uint(x);
    uint hx = (ux + 0x7FFFu + ((ux >> 16) & 1u)) & 0xFFFF0000u;
    float rx = x - __uint_as_float(hx);
    uint urx = __float_as_uint(rx);
    uint lx = (urx + 0x7FFFu + ((urx >> 16) & 1u)) >> 16;
    uint uy = __float_as_uint(y);
    uint hy = (uy + 0x7FFFu + ((uy >> 16) & 1u)) & 0xFFFF0000u;
    float ry = y - __uint_as_float(hy);
    uint ury = __float_as_uint(ry);
    uint ly = (ury + 0x7FFFu + ((ury >> 16) & 1u)) >> 16;
    return make_uint2((hx >> 16) | (hy & 0xFFFF0000u), lx | (ly << 16));
}

__global__ void k_count(const int* __restrict__ dst, int* __restrict__ counts, int e) {
    int i = blockIdx.x * blockDim.x + threadIdx.x;
    if (i < e) atomicAdd(&counts[dst[i]], 1);
}

// --- coalesced 3-kernel exclusive scan over counts[NSEG*SEG] (padding zeroed) ---
__global__ __launch_bounds__(256) void k_scan_seg(const int* __restrict__ counts,
                                                  int* __restrict__ segscan,
                                                  int* __restrict__ segtot) {
    const int b = blockIdx.x, t = threadIdx.x;
    const int base = b * SEG + t * 4;
    const int4 v = *(const int4*)(counts + base);
    const int s0 = v.x, s1 = s0 + v.y, s2 = s1 + v.z, s3 = s2 + v.w;
    __shared__ int sl[256];
    sl[t] = s3;
    __syncthreads();
    for (int off = 1; off < 256; off <<= 1) {
        int add = (t >= off) ? sl[t - off] : 0;
        __syncthreads();
        sl[t] += add;
        __syncthreads();
    }
    const int tp = sl[t] - s3;
    int4 o;
    o.x = tp; o.y = tp + s0; o.z = tp + s1; o.w = tp + s2;
    *(int4*)(segscan + base) = o;
    if (t == 255) segtot[b] = sl[255];
}

__global__ void k_scan_tot(const int* __restrict__ segtot, int* __restrict__ segbase) {
    const int t = threadIdx.x;  // 64 threads, 1 block
    const int v = (t < NSEG) ? segtot[t] : 0;
    int s = v;
#pragma unroll
    for (int off = 1; off < 64; off <<= 1) {
        int u = __shfl_up(s, off, 64);
        if (t >= off) s += u;
    }
    if (t <= NSEG) segbase[t] = s - v;
}

__global__ void k_scan_fin(const int* __restrict__ segscan, const int* __restrict__ segbase,
                           int* __restrict__ offsets, int* __restrict__ cursor) {
    const int i = blockIdx.x * blockDim.x + threadIdx.x;
    if (i < N_NODES) {
        const int val = segbase[i >> 10] + segscan[i];
        offsets[i] = val;
        cursor[i] = val;
    } else if (i == N_NODES) {
        offsets[N_NODES] = segbase[NSEG];
    }
}

__global__ void k_fill(const int* __restrict__ src, const int* __restrict__ dst,
                       const int* __restrict__ etype, int* cursor,
                       int* __restrict__ edges, int e) {
    int i = blockIdx.x * blockDim.x + threadIdx.x;
    if (i < e) {
        int d = dst[i];
        int pos = atomicAdd(&cursor[d], 1);
        edges[pos] = src[i] | (etype[i] << 16);
    }
}

// Pack bases [K=1024][N=128] fp32 into MFMA-B-fragment-ordered bf16 hi/lo:
// layout [kt:32][n:128][kk:32] ushort. Thread mapping chosen for coalesced WRITES.
__global__ void k_packB(const float* __restrict__ bases, ushort* __restrict__ Bhi,
                        ushort* __restrict__ Blo) {
    int id = blockIdx.x * blockDim.x + threadIdx.x;  // 131072
    int kk = id & 31, nn = (id >> 5) & 127, kt = id >> 12;
    int k = kt * 32 + kk;
    float v = bases[(size_t)k * DIM + nn];
    uint u = __float_as_uint(v);
    uint hu = (u + 0x7FFFu + ((u >> 16) & 1u)) & 0xFFFF0000u;
    float rf = v - __uint_as_float(hu);
    uint ur = __float_as_uint(rf);
    uint lu = (ur + 0x7FFFu + ((ur >> 16) & 1u)) >> 16;
    int off = kt * 4096 + nn * 32 + kk;  // == id -> coalesced
    Bhi[off] = (ushort)(hu >> 16);
    Blo[off] = (ushort)lu;
}

// One RGCN layer, fused, 512 threads (8 waves):
//  phase 1: one node per HALF-WAVE, 4 dims/lane (16B gathers), DEPTH-3
//           pipeline: descriptors 3 batches ahead, gathers 2 ahead (~8 x-row
//           loads in flight per half-wave). comp in LDS. Tail gathers issued
//           together before consumption. bf16 hi/lo to MFMA-packed swizzled LDS.
//  phase 2: wave owns one 16-col strip; [16 x 1024] @ [1024 x 128] via
//           mfma_f32_16x16x32_bf16, 3-term split (fp32-class accuracy).
//  GATE (layer 3): epilogue computes gate[n] = h3[n,:].gw + gb via 16-lane
//           shuffle reduce + per-wave LDS partials (NO ATOMICS — see R7).
//
// PITFALL (R3): do NOT scalarize loads of per-call-rebuilt arrays
// (edges/offsets/...) — compiler s_load via scalar cache serves STALE data on
// graph replay. Keep lane-derived (vector) addressing for those.
// PITFALL (R7): NO per-lane float atomicAdd on LDS — compiles to a CAS loop
// (serial ds_read/ds_cmpst chain), 3.4x regression measured.
template <bool RELU, bool GATE>
__global__ __launch_bounds__(512, 4) void k_layer(
    const float* __restrict__ xin, float* __restrict__ hout,
    const int* __restrict__ edges, const int* __restrict__ offsets,
    const float* __restrict__ comp,
    const ushort* __restrict__ Bhi, const ushort* __restrict__ Blo,
    const float* __restrict__ bias,
    const float* __restrict__ gw, const float* __restrict__ gb,
    float* __restrict__ gate) {
    __shared__ ushort sHi[NB * KDIM];  // 32 KiB
    __shared__ ushort sLo[NB * KDIM];  // 32 KiB
    __shared__ float scomp[N_REL * 8];
    __shared__ float sgatep[NB][8];
    const int tid = threadIdx.x;
    if (tid < 64) scomp[tid] = comp[tid];
    __syncthreads();

    // ---- phase 1: edge aggregation; one node per half-wave, 4 dims/lane ----
    {
        const int nl = tid >> 5;         // 0..15 — this half-wave's node
        const int l5 = tid & 31;
        const int d0 = l5 * 4;           // this lane's 4 dims
        const int kt_off = l5 >> 3;      // 0..3
        const int q = (l5 >> 1) & 3;
        const int jb = (l5 & 1) * 4;
        const int n = blockIdx.x * NB + nl;
        f32x4 acc[N_BASES];
#pragma unroll
        for (int b = 0; b < N_BASES; b++) acc[b] = (f32x4)0.f;
        const int e0 = offsets[n], e1 = offsets[n + 1];
        const int nb4 = (e1 - e0) >> 2;

        int pa0 = 0, pa1 = 0, pa2 = 0, pa3 = 0;  // batch i (being consumed)
        int pb0 = 0, pb1 = 0, pb2 = 0, pb3 = 0;  // batch i+1
        int pc0 = 0, pc1 = 0, pc2 = 0, pc3 = 0;  // batch i+2
        f32x4 va0, va1, va2, va3;                // gathers batch i
        f32x4 vb0, vb1, vb2, vb3;                // gathers batch i+1
        if (0 < nb4) { const int ee = e0;     pa0 = edges[ee]; pa1 = edges[ee + 1]; pa2 = edges[ee + 2]; pa3 = edges[ee + 3]; }
        if (1 < nb4) { const int ee = e0 + 4; pb0 = edges[ee]; pb1 = edges[ee + 1]; pb2 = edges[ee + 2]; pb3 = edges[ee + 3]; }
        if (2 < nb4) { const int ee = e0 + 8; pc0 = edges[ee]; pc1 = edges[ee + 1]; pc2 = edges[ee + 2]; pc3 = edges[ee + 3]; }
        if (0 < nb4) {
            va0 = *(const f32x4*)(xin + (size_t)(pa0 & 0xFFFF) * DIM + d0);
            va1 = *(const f32x4*)(xin + (size_t)(pa1 & 0xFFFF) * DIM + d0);
            va2 = *(const f32x4*)(xin + (size_t)(pa2 & 0xFFFF) * DIM + d0);
            va3 = *(const f32x4*)(xin + (size_t)(pa3 & 0xFFFF) * DIM + d0);
        }
        if (1 < nb4) {
            vb0 = *(const f32x4*)(xin + (size_t)(pb0 & 0xFFFF) * DIM + d0);
            vb1 = *(const f32x4*)(xin + (size_t)(pb1 & 0xFFFF) * DIM + d0);
            vb2 = *(const f32x4*)(xin + (size_t)(pb2 & 0xFFFF) * DIM + d0);
            vb3 = *(const f32x4*)(xin + (size_t)(pb3 & 0xFFFF) * DIM + d0);
        }
        for (int i = 0; i < nb4; ++i) {
            // 1) descriptors for batch i+3
            int pd0 = 0, pd1 = 0, pd2 = 0, pd3 = 0;
            if (i + 3 < nb4) {
                const int ee = e0 + (i + 3) * 4;
                pd0 = edges[ee]; pd1 = edges[ee + 1]; pd2 = edges[ee + 2]; pd3 = edges[ee + 3];
            }
            // 2) gathers for batch i+2
            f32x4 vc0, vc1, vc2, vc3;
            if (i + 2 < nb4) {
                vc0 = *(const f32x4*)(xin + (size_t)(pc0 & 0xFFFF) * DIM + d0);
                vc1 = *(const f32x4*)(xin + (size_t)(pc1 & 0xFFFF) * DIM + d0);
                vc2 = *(const f32x4*)(xin + (size_t)(pc2 & 0xFFFF) * DIM + d0);
                vc3 = *(const f32x4*)(xin + (size_t)(pc3 & 0xFFFF) * DIM + d0);
            }
            // 3) FMA batch i (gathers issued two iterations ago)
            const float4 ca0 = *(const float4*)&scomp[(pa0 >> 16) * 8];
            const float4 cb0 = *(const float4*)&scomp[(pa0 >> 16) * 8 + 4];
            const float4 ca1 = *(const float4*)&scomp[(pa1 >> 16) * 8];
            const float4 cb1 = *(const float4*)&scomp[(pa1 >> 16) * 8 + 4];
            const float4 ca2 = *(const float4*)&scomp[(pa2 >> 16) * 8];
            const float4 cb2 = *(const float4*)&scomp[(pa2 >> 16) * 8 + 4];
            const float4 ca3 = *(const float4*)&scomp[(pa3 >> 16) * 8];
            const float4 cb3 = *(const float4*)&scomp[(pa3 >> 16) * 8 + 4];
            const float cw0[8] = {ca0.x, ca0.y, ca0.z, ca0.w, cb0.x, cb0.y, cb0.z, cb0.w};
            const float cw1[8] = {ca1.x, ca1.y, ca1.z, ca1.w, cb1.x, cb1.y, cb1.z, cb1.w};
            const float cw2[8] = {ca2.x, ca2.y, ca2.z, ca2.w, cb2.x, cb2.y, cb2.z, cb2.w};
            const float cw3[8] = {ca3.x, ca3.y, ca3.z, ca3.w, cb3.x, cb3.y, cb3.z, cb3.w};
#pragma unroll
            for (int b = 0; b < 8; b++) {
                acc[b] = __builtin_elementwise_fma((f32x4)cw0[b], va0, acc[b]);
                acc[b] = __builtin_elementwise_fma((f32x4)cw1[b], va1, acc[b]);
                acc[b] = __builtin_elementwise_fma((f32x4)cw2[b], va2, acc[b]);
                acc[b] = __builtin_elementwise_fma((f32x4)cw3[b], va3, acc[b]);
            }
            // rotate
            pa0 = pb0; pa1 = pb1; pa2 = pb2; pa3 = pb3;
            pb0 = pc0; pb1 = pc1; pb2 = pc2; pb3 = pc3;
            pc0 = pd0; pc1 = pd1; pc2 = pd2; pc3 = pd3;
            va0 = vb0; va1 = vb1; va2 = vb2; va3 = vb3;
            vb0 = vc0; vb1 = vc1; vb2 = vc2; vb3 = vc3;
        }
        // tail (0..3 edges): issue all gathers first, then consume
        {
            const int et = e0 + nb4 * 4;
            const int rem = e1 - et;
            int pt0 = 0, pt1 = 0, pt2 = 0;
            if (rem > 0) pt0 = edges[et];
            if (rem > 1) pt1 = edges[et + 1];
            if (rem > 2) pt2 = edges[et + 2];
            f32x4 vt0, vt1, vt2;
            if (rem > 0) vt0 = *(const f32x4*)(xin + (size_t)(pt0 & 0xFFFF) * DIM + d0);
            if (rem > 1) vt1 = *(const f32x4*)(xin + (size_t)(pt1 & 0xFFFF) * DIM + d0);
            if (rem > 2) vt2 = *(const f32x4*)(xin + (size_t)(pt2 & 0xFFFF) * DIM + d0);
            if (rem > 0) {
                const float4 ca = *(const float4*)&scomp[(pt0 >> 16) * 8];
                const float4 cb = *(const float4*)&scomp[(pt0 >> 16) * 8 + 4];
                const float cw[8] = {ca.x, ca.y, ca.z, ca.w, cb.x, cb.y, cb.z, cb.w};
#pragma unroll
                for (int b = 0; b < 8; b++) acc[b] = __builtin_elementwise_fma((f32x4)cw[b], vt0, acc[b]);
            }
            if (rem > 1) {
                const float4 ca = *(const float4*)&scomp[(pt1 >> 16) * 8];
                const float4 cb = *(const float4*)&scomp[(pt1 >> 16) * 8 + 4];
                const float cw[8] = {ca.x, ca.y, ca.z, ca.w, cb.x, cb.y, cb.z, cb.w};
#pragma unroll
                for (int b = 0; b < 8; b++) acc[b] = __builtin_elementwise_fma((f32x4)cw[b], vt1, acc[b]);
            }
            if (rem > 2) {
                const float4 ca = *(const float4*)&scomp[(pt2 >> 16) * 8];
                const float4 cb = *(const float4*)&scomp[(pt2 >> 16) * 8 + 4];
                const float cw[8] = {ca.x, ca.y, ca.z, ca.w, cb.x, cb.y, cb.z, cb.w};
#pragma unroll
                for (int b = 0; b < 8; b++) acc[b] = __builtin_elementwise_fma((f32x4)cw[b], vt2, acc[b]);
            }
        }
        // write 4 bf16 hi + 4 bf16 lo per basis to swizzled LDS
#pragma unroll
        for (int b = 0; b < 8; b++) {
            const int kt = b * 4 + kt_off;
            const int chunk = q * 16 + ((nl ^ q) ^ ((kt & 1) << 2));
            const int uoff = kt * 512 + chunk * 8 + jb;  // ushort offset, 8B aligned
            const uint2 p01 = split2(acc[b].x, acc[b].y);
            const uint2 p23 = split2(acc[b].z, acc[b].w);
            *(uint2*)(sHi + uoff) = make_uint2(p01.x, p23.x);
            *(uint2*)(sLo + uoff) = make_uint2(p01.y, p23.y);
        }
    }
    __syncthreads();

    // ---- phase 2: MFMA GEMM, each of 8 waves owns one 16-col strip ----
    const int w = tid >> 6;
    const int lane = tid & 63;
    const int q2 = lane >> 4, mm = lane & 15;
    const int a_even = (q2 * 16 + (mm ^ q2)) * 8;        // kt even
    const int a_odd  = (q2 * 16 + ((mm ^ q2) ^ 4)) * 8;  // kt odd (parity swizzle)
    const int n0 = w * 16 + mm;
    const ushort* bph = Bhi + n0 * 32 + q2 * 8;
    const ushort* bpl = Blo + n0 * 32 + q2 * 8;
    floatx4 acc0 = {0.f, 0.f, 0.f, 0.f};
    for (int kt = 0; kt < 32; kt += 2) {
        {
            const short8 ah = *(const short8*)(sHi + kt * 512 + a_even);
            const short8 al = *(const short8*)(sLo + kt * 512 + a_even);
            const short8 bh = *(const short8*)(bph + kt * 4096);
            const short8 bl = *(const short8*)(bpl + kt * 4096);
            acc0 = __builtin_amdgcn_mfma_f32_16x16x32_bf16(ah, bh, acc0, 0, 0, 0);
            acc0 = __builtin_amdgcn_mfma_f32_16x16x32_bf16(ah, bl, acc0, 0, 0, 0);
            acc0 = __builtin_amdgcn_mfma_f32_16x16x32_bf16(al, bh, acc0, 0, 0, 0);
        }
        {
            const int kto = kt + 1;
            const short8 ah = *(const short8*)(sHi + kto * 512 + a_odd);
            const short8 al = *(const short8*)(sLo + kto * 512 + a_odd);
            const short8 bh = *(const short8*)(bph + kto * 4096);
            const short8 bl = *(const short8*)(bpl + kto * 4096);
            acc0 = __builtin_amdgcn_mfma_f32_16x16x32_bf16(ah, bh, acc0, 0, 0, 0);
            acc0 = __builtin_amdgcn_mfma_f32_16x16x32_bf16(ah, bl, acc0, 0, 0, 0);
            acc0 = __builtin_amdgcn_mfma_f32_16x16x32_bf16(al, bh, acc0, 0, 0, 0);
        }
    }
    const float b0 = bias[n0];
    float gp[4];
#pragma unroll
    for (int r = 0; r < 4; r++) {
        const int node = blockIdx.x * NB + q2 * 4 + r;  // C/D: row=(lane>>4)*4+reg, col=lane&15
        float v0 = acc0[r] + b0;
        if (RELU) v0 = fmaxf(v0, 0.f);
        hout[(size_t)node * DIM + n0] = v0;
        if (GATE) gp[r] = v0 * gw[n0];
    }
    if (GATE) {
        // reduce over the 16 cols (mm) within each 16-lane group
#pragma unroll
        for (int r = 0; r < 4; r++) {
#pragma unroll
            for (int s = 1; s < 16; s <<= 1) gp[r] += __shfl_xor(gp[r], s, 16);
        }
        if (mm == 0) {
#pragma unroll
            for (int r = 0; r < 4; r++) sgatep[q2 * 4 + r][w] = gp[r];
        }
        __syncthreads();
        if (tid < NB) {
            float s = 0.f;
#pragma unroll
            for (int w8 = 0; w8 < 8; w8++) s += sgatep[tid][w8];
            gate[blockIdx.x * NB + tid] = s + gb[0];
        }
    }
}

// One block (256 threads) per graph: segment softmax + weighted readout + MLP head + sigmoid.
__global__ __launch_bounds__(256) void k_pool(
    const float* __restrict__ h3, const float* __restrict__ gate, const int* __restrict__ n2g,
    const float* __restrict__ fc1w, const float* __restrict__ fc1b,
    const float* __restrict__ fc2w, const float* __restrict__ fc2b,
    const float* __restrict__ fc3w, const float* __restrict__ fc3b,
    float* __restrict__ out, int N) {
    const int g = blockIdx.x;
    const int tid = threadIdx.x;
    __shared__ float sred[256];
    __shared__ float sr[128];
    __shared__ float sz1[100];
    __shared__ float sz2[64];
    __shared__ float sm, ssum;

    const int s = lower_bound_i(n2g, N, g);
    const int e = lower_bound_i(n2g, N, g + 1);

    float m = -3.4e38f;
    for (int n = s + tid; n < e; n += 256) m = fmaxf(m, gate[n]);
    sred[tid] = m;
    __syncthreads();
    for (int off = 128; off > 0; off >>= 1) {
        if (tid < off) sred[tid] = fmaxf(sred[tid], sred[tid + off]);
        __syncthreads();
    }
    if (tid == 0) sm = sred[0];
    __syncthreads();
    const float mm = sm;

    float sum = 0.f;
    for (int n = s + tid; n < e; n += 256) sum += expf(gate[n] - mm);
    sred[tid] = sum;
    __syncthreads();
    for (int off = 128; off > 0; off >>= 1) {
        if (tid < off) sred[tid] += sred[tid + off];
        __syncthreads();
    }
    if (tid == 0) ssum = sred[0];
    __syncthreads();
    const float inv = (e > s) ? 1.0f / ssum : 0.f;

    // weighted readout: col = tid&127, node stream split across two halves
    const int col = tid & 127;
    const int half = tid >> 7;
    float acc = 0.f;
    int n = s + half;
    for (; n + 2 < e; n += 4) {
        const float w0 = expf(gate[n] - mm);
        const float w1 = expf(gate[n + 2] - mm);
        const float a0 = h3[(size_t)n * DIM + col];
        const float a1 = h3[(size_t)(n + 2) * DIM + col];
        acc = fmaf(w0, a0, acc);
        acc = fmaf(w1, a1, acc);
    }
    for (; n < e; n += 2) {
        const float wgt = expf(gate[n] - mm);
        acc = fmaf(wgt, h3[(size_t)n * DIM + col], acc);
    }
    sred[tid] = acc;
    __syncthreads();
    if (tid < 128) sr[tid] = (sred[tid] + sred[tid + 128]) * inv;
    __syncthreads();

    if (tid < 100) {
        float t = fc1b[tid];
        for (int i = 0; i < 128; i++) t = fmaf(sr[i], fc1w[i * 100 + tid], t);
        sz1[tid] = fmaxf(t, 0.f);
    }
    __syncthreads();
    if (tid < 64) {
        float t = fc2b[tid];
        for (int i = 0; i < 100; i++) t = fmaf(sz1[i], fc2w[i * 64 + tid], t);
        sz2[tid] = fmaxf(t, 0.f);
    }
    __syncthreads();
    if (tid < 64) {
        float p = sz2[tid] * fc3w[tid];
#pragma unroll
        for (int off = 32; off > 0; off >>= 1) p += __shfl_down(p, off, 64);
        if (tid == 0) {
            const float z = p + fc3b[0];
            out[g] = 1.0f / (1.0f + expf(-z));
        }
    }
}

extern "C" void kernel_launch(void* const* d_in, const int* in_sizes, int n_in,
                              void* d_out, int out_size, void* d_ws, size_t ws_size,
                              hipStream_t stream) {
    (void)in_sizes; (void)n_in; (void)out_size; (void)ws_size;
    const float* features = (const float*)d_in[0];
    const int*   src      = (const int*)d_in[1];
    const int*   dst      = (const int*)d_in[2];
    const int*   etype    = (const int*)d_in[3];
    const int*   n2g      = (const int*)d_in[4];
    const float* bases1   = (const float*)d_in[5];
    const float* comp1    = (const float*)d_in[6];
    const float* bias1    = (const float*)d_in[7];
    const float* bases2   = (const float*)d_in[8];
    const float* comp2    = (const float*)d_in[9];
    const float* bias2    = (const float*)d_in[10];
    const float* bases3   = (const float*)d_in[11];
    const float* comp3    = (const float*)d_in[12];
    const float* bias3    = (const float*)d_in[13];
    const float* gate_w   = (const float*)d_in[14];
    const float* gate_b   = (const float*)d_in[15];
    const float* fc1w     = (const float*)d_in[16];
    const float* fc1b     = (const float*)d_in[17];
    const float* fc2w     = (const float*)d_in[18];
    const float* fc2b     = (const float*)d_in[19];
    const float* fc3w     = (const float*)d_in[20];
    const float* fc3b     = (const float*)d_in[21];
    float* out = (float*)d_out;

    char* w = (char*)d_ws;
    auto alloc = [&](size_t bytes) -> char* {
        char* p = w;
        w += (bytes + 255) & ~(size_t)255;
        return p;
    };
    int*    offsets = (int*)alloc((N_NODES + 1) * sizeof(int));
    int*    cursor  = (int*)alloc((size_t)NSEG * SEG * sizeof(int));  // counts (padded), then fill cursor
    int*    edges   = (int*)alloc(N_EDGES * sizeof(int));
    int*    segscan = (int*)alloc((size_t)NSEG * SEG * sizeof(int));
    int*    segtot  = (int*)alloc(64 * sizeof(int));
    int*    segbase = (int*)alloc(64 * sizeof(int));
    float*  hA      = (float*)alloc((size_t)N_NODES * DIM * sizeof(float));
    float*  hB      = (float*)alloc((size_t)N_NODES * DIM * sizeof(float));
    float*  gate    = (float*)alloc(N_NODES * sizeof(float));
    ushort* Bhi1    = (ushort*)alloc((size_t)KDIM * DIM * sizeof(ushort));
    ushort* Blo1    = (ushort*)alloc((size_t)KDIM * DIM * sizeof(ushort));
    ushort* Bhi2    = (ushort*)alloc((size_t)KDIM * DIM * sizeof(ushort));
    ushort* Blo2    = (ushort*)alloc((size_t)KDIM * DIM * sizeof(ushort));
    ushort* Bhi3    = (ushort*)alloc((size_t)KDIM * DIM * sizeof(ushort));
    ushort* Blo3    = (ushort*)alloc((size_t)KDIM * DIM * sizeof(ushort));

    // weight packing (bf16 hi/lo, MFMA fragment order)
    k_packB<<<(KDIM * DIM) / 256, 256, 0, stream>>>(bases1, Bhi1, Blo1);
    k_packB<<<(KDIM * DIM) / 256, 256, 0, stream>>>(bases2, Bhi2, Blo2);
    k_packB<<<(KDIM * DIM) / 256, 256, 0, stream>>>(bases3, Bhi3, Blo3);

    // CSR by dst (rebuilt every call)
    hipMemsetAsync(cursor, 0, (size_t)NSEG * SEG * sizeof(int), stream);
    k_count<<<(N_EDGES + 255) / 256, 256, 0, stream>>>(dst, cursor, N_EDGES);
    k_scan_seg<<<NSEG, 256, 0, stream>>>(cursor, segscan, segtot);
    k_scan_tot<<<1, 64, 0, stream>>>(segtot, segbase);
    k_scan_fin<<<(N_NODES + 256) / 256, 256, 0, stream>>>(segscan, segbase, offsets, cursor);
    k_fill<<<(N_EDGES + 255) / 256, 256, 0, stream>>>(src, dst, etype, cursor, edges, N_EDGES);

    // 3 RGCN layers (aggregate-first + fused MFMA GEMM; layer 3 fuses gate)
    k_layer<true, false><<<N_NODES / NB, 512, 0, stream>>>(features, hA, edges, offsets, comp1, Bhi1, Blo1, bias1, gate_w, gate_b, gate);
    k_layer<true, false><<<N_NODES / NB, 512, 0, stream>>>(hA, hB, edges, offsets, comp2, Bhi2, Blo2, bias2, gate_w, gate_b, gate);
    k_layer<false, true><<<N_NODES / NB, 512, 0, stream>>>(hB, hA, edges, offsets, comp3, Bhi3, Blo3, bias3, gate_w, gate_b, gate);

    // pooling + MLP head (gate computed in layer 3)
    k_pool<<<N_GRAPHS, 256, 0, stream>>>(hA, gate, n2g, fc1w, fc1b, fc2w, fc2b, fc3w, fc3b, out, N_NODES);
}

// Round 9
// 595.998 us; speedup vs baseline: 2.7835x; 1.0472x over previous
//
#include <hip/hip_runtime.h>
#include <hip/hip_bf16.h>
#include <math.h>

#define N_NODES 50000
#define N_EDGES 600000
#define DIM 128
#define N_REL 8
#define N_GRAPHS 256
#define NB 16                 // nodes per block in layer kernel (50000 = 3125*16 exact)
#define KDIM (N_REL * DIM)    // relation-stacked K = 1024
#define NKEY (N_NODES * N_REL)  // 400000 (node,rel) keys
#define SEG 1024
#define NSEG2 391             // ceil(400000/1024); NSEG2*SEG = 400384

typedef __attribute__((ext_vector_type(8))) short short8;
typedef __attribute__((ext_vector_type(4))) float floatx4;
typedef __attribute__((ext_vector_type(4))) float f32x4;
typedef unsigned int uint;
typedef unsigned short ushort;

static __device__ __forceinline__ int lower_bound_i(const int* a, int n, int v) {
    int lo = 0, hi = n;
    while (lo < hi) { int mid = (lo + hi) >> 1; if (a[mid] < v) lo = mid + 1; else hi = mid; }
    return lo;
}

// RNE float->bf16 split: hiword = bf16(x)|bf16(y)<<16 ; loword = bf16(x-hi)|bf16(y-hi)<<16
static __device__ __forceinline__ uint2 split2(float x, float y) {
    uint ux = __float_as_uint(x);
    uint hx = (ux + 0x7FFFu + ((ux >> 16) & 1u)) & 0xFFFF0000u;
    float rx = x - __uint_as_float(hx);
    uint urx = __float_as_uint(rx);
    uint lx = (urx + 0x7FFFu + ((urx >> 16) & 1u)) >> 16;
    uint uy = __float_as_uint(y);
    uint hy = (uy + 0x7FFFu + ((uy >> 16) & 1u)) & 0xFFFF0000u;
    float ry = y - __uint_as_float(hy);
    uint ury = __float_as_uint(ry);
    uint ly = (ury + 0x7FFFu + ((ury >> 16) & 1u)) >> 16;
    return make_uint2((hx >> 16) | (hy & 0xFFFF0000u), lx | (ly << 16));
}

__global__ void k_count(const int* __restrict__ dst, const int* __restrict__ etype,
                        int* __restrict__ counts, int e) {
    int i = blockIdx.x * blockDim.x + threadIdx.x;
    if (i < e) atomicAdd(&counts[dst[i] * 8 + etype[i]], 1);
}

// --- coalesced 3-kernel exclusive scan over counts[NSEG2*SEG] (padding zeroed) ---
__global__ __launch_bounds__(256) void k_scan_seg(const int* __restrict__ counts,
                                                  int* __restrict__ segscan,
                                                  int* __restrict__ segtot) {
    const int b = blockIdx.x, t = threadIdx.x;
    const int base = b * SEG + t * 4;
    const int4 v = *(const int4*)(counts + base);
    const int s0 = v.x, s1 = s0 + v.y, s2 = s1 + v.z, s3 = s2 + v.w;
    __shared__ int sl[256];
    sl[t] = s3;
    __syncthreads();
    for (int off = 1; off < 256; off <<= 1) {
        int add = (t >= off) ? sl[t - off] : 0;
        __syncthreads();
        sl[t] += add;
        __syncthreads();
    }
    const int tp = sl[t] - s3;
    int4 o;
    o.x = tp; o.y = tp + s0; o.z = tp + s1; o.w = tp + s2;
    *(int4*)(segscan + base) = o;
    if (t == 255) segtot[b] = sl[255];
}

__global__ __launch_bounds__(512) void k_scan_tot(const int* __restrict__ segtot,
                                                  int* __restrict__ segbase) {
    const int t = threadIdx.x;  // 512 threads, 1 block
    const int v = (t < NSEG2) ? segtot[t] : 0;
    __shared__ int sl[512];
    sl[t] = v;
    __syncthreads();
    for (int off = 1; off < 512; off <<= 1) {
        int u = (t >= off) ? sl[t - off] : 0;
        __syncthreads();
        sl[t] += u;
        __syncthreads();
    }
    if (t < NSEG2) segbase[t] = sl[t] - v;
    if (t == NSEG2) segbase[NSEG2] = sl[NSEG2 - 1];
}

__global__ void k_scan_fin(const int* __restrict__ segscan, const int* __restrict__ segbase,
                           int* __restrict__ offsets, int* __restrict__ cursor) {
    const int i = blockIdx.x * blockDim.x + threadIdx.x;
    if (i < NKEY) {
        const int val = segbase[i >> 10] + segscan[i];
        offsets[i] = val;
        cursor[i] = val;
    } else if (i == NKEY) {
        offsets[NKEY] = segbase[NSEG2];
    }
}

// scatter edges grouped by (dst, etype); word = src(16b) | etype(3b @16)
__global__ void k_fill(const int* __restrict__ src, const int* __restrict__ dst,
                       const int* __restrict__ etype, int* cursor,
                       int* __restrict__ edges, int e) {
    int i = blockIdx.x * blockDim.x + threadIdx.x;
    if (i < e) {
        const int et = etype[i];
        int pos = atomicAdd(&cursor[dst[i] * 8 + et], 1);
        edges[pos] = src[i] | (et << 16);
    }
}

// W[k=r*128+dk][col] = sum_b comp[r,b]*bases[b][dk][col], packed bf16 hi/lo into
// MFMA-B-fragment order [kt:32][col:128][kk:32] ushort. (Verified in R7.)
__global__ void k_packW(const float* __restrict__ bases, const float* __restrict__ comp,
                        ushort* __restrict__ Whi, ushort* __restrict__ Wlo) {
    int id = blockIdx.x * blockDim.x + threadIdx.x;  // 131072
    int nn = id & 127, k = id >> 7;
    int r = k >> 7, dk = k & 127;
    const float* cp = comp + r * 8;
    float v = 0.f;
#pragma unroll
    for (int b = 0; b < 8; b++) v = fmaf(cp[b], bases[((size_t)b * 128 + dk) * 128 + nn], v);
    uint u = __float_as_uint(v);
    uint hu = (u + 0x7FFFu + ((u >> 16) & 1u)) & 0xFFFF0000u;
    float rf = v - __uint_as_float(hu);
    uint ur = __float_as_uint(rf);
    uint lu = (ur + 0x7FFFu + ((ur >> 16) & 1u)) >> 16;
    int kt = k >> 5, kk = k & 31;
    int off = kt * 4096 + nn * 32 + kk;
    Whi[off] = (ushort)(hu >> 16);
    Wlo[off] = (ushort)lu;
}

// One RGCN layer, fused, 512 threads (8 waves):
//  phase 1: RELATION-SORTED edge aggregation. One node per half-wave, 4 dims/
//           lane (16B gathers), depth-2/3 batch pipeline. Edges are grouped by
//           (node, relation), so per edge the consume is tmp += v (2 pk-adds);
//           on relation change (<=8/node) tmp is flushed as bf16 hi/lo into
//           the relation-stacked A-fragment LDS slot. No per-edge comp FMAs.
//           LDS A-region zeroed first (empty relations stay 0).
//  phase 2: wave owns one 16-col strip; [16 x 1024] @ [1024 x 128] via
//           mfma_f32_16x16x32_bf16, 3-term split, B = relation-stacked W
//           (comp folded by k_packW).
//  GATE (layer 3): epilogue computes gate[n] via 16-lane shuffle reduce +
//           per-wave LDS partials (NO ATOMICS — R7 pitfall).
//
// PITFALL (R3): do NOT scalarize loads of per-call-rebuilt arrays
// (edges/offsets) — compiler s_load via scalar cache serves STALE data on
// graph replay. Keep lane-derived (vector) addressing.
// PITFALL (R7): NO per-lane float atomicAdd on LDS — compiles to CAS loop.
template <bool RELU, bool GATE>
__global__ __launch_bounds__(512, 4) void k_layer(
    const float* __restrict__ xin, float* __restrict__ hout,
    const int* __restrict__ edges, const int* __restrict__ offsets,
    const ushort* __restrict__ Whi, const ushort* __restrict__ Wlo,
    const float* __restrict__ bias,
    const float* __restrict__ gw, const float* __restrict__ gb,
    float* __restrict__ gate) {
    __shared__ ushort sHi[NB * KDIM];  // 32 KiB
    __shared__ ushort sLo[NB * KDIM];  // 32 KiB
    __shared__ float sgatep[NB][8];
    const int tid = threadIdx.x;

    // zero A-fragment LDS (empty (node,rel) slots must contribute 0)
    {
        uint4 z = make_uint4(0u, 0u, 0u, 0u);
#pragma unroll
        for (int i = 0; i < 4; ++i) {
            ((uint4*)sHi)[tid + i * 512] = z;
            ((uint4*)sLo)[tid + i * 512] = z;
        }
    }
    __syncthreads();

    // ---- phase 1: relation-sorted aggregation; one node per half-wave ----
    {
        const int nl = tid >> 5;         // 0..15 — this half-wave's node
        const int l5 = tid & 31;
        const int d0 = l5 * 4;           // this lane's 4 dims
        const int kt_off = l5 >> 3;      // 0..3
        const int q = (l5 >> 1) & 3;
        const int jb = (l5 & 1) * 4;
        const int n = blockIdx.x * NB + nl;
        const int e0 = offsets[n * 8];
        const int e1 = offsets[n * 8 + 8];
        f32x4 tmp = (f32x4)0.f;
        int rcur = -1;

#define FLUSH_FRAG(RRR)                                                        \
        {                                                                      \
            const int kt = (RRR) * 4 + kt_off;                                 \
            const int chunk = q * 16 + ((nl ^ q) ^ ((kt & 1) << 2));           \
            const int uoff = kt * 512 + chunk * 8 + jb;                        \
            const uint2 p01 = split2(tmp.x, tmp.y);                            \
            const uint2 p23 = split2(tmp.z, tmp.w);                            \
            *(uint2*)(sHi + uoff) = make_uint2(p01.x, p23.x);                  \
            *(uint2*)(sLo + uoff) = make_uint2(p01.y, p23.y);                  \
        }

#define CONSUME_EDGE(PK, VV)                                                   \
        {                                                                      \
            const int r_ = ((PK) >> 16) & 7;                                   \
            if (r_ != rcur) {                                                  \
                if (rcur >= 0) FLUSH_FRAG(rcur);                               \
                rcur = r_;                                                     \
                tmp = (VV);                                                    \
            } else {                                                           \
                tmp += (VV);                                                   \
            }                                                                  \
        }

        const int nb4 = (e1 - e0) >> 2;
        int pa0 = 0, pa1 = 0, pa2 = 0, pa3 = 0;  // batch i
        int pb0 = 0, pb1 = 0, pb2 = 0, pb3 = 0;  // batch i+1
        f32x4 va0, va1, va2, va3;
        if (0 < nb4) { const int ee = e0;     pa0 = edges[ee]; pa1 = edges[ee + 1]; pa2 = edges[ee + 2]; pa3 = edges[ee + 3]; }
        if (1 < nb4) { const int ee = e0 + 4; pb0 = edges[ee]; pb1 = edges[ee + 1]; pb2 = edges[ee + 2]; pb3 = edges[ee + 3]; }
        if (0 < nb4) {
            va0 = *(const f32x4*)(xin + (size_t)(pa0 & 0xFFFF) * DIM + d0);
            va1 = *(const f32x4*)(xin + (size_t)(pa1 & 0xFFFF) * DIM + d0);
            va2 = *(const f32x4*)(xin + (size_t)(pa2 & 0xFFFF) * DIM + d0);
            va3 = *(const f32x4*)(xin + (size_t)(pa3 & 0xFFFF) * DIM + d0);
        }
        for (int i = 0; i < nb4; ++i) {
            // descriptors for batch i+2
            int pc0 = 0, pc1 = 0, pc2 = 0, pc3 = 0;
            if (i + 2 < nb4) {
                const int ee = e0 + (i + 2) * 4;
                pc0 = edges[ee]; pc1 = edges[ee + 1]; pc2 = edges[ee + 2]; pc3 = edges[ee + 3];
            }
            // gathers for batch i+1
            f32x4 vb0, vb1, vb2, vb3;
            if (i + 1 < nb4) {
                vb0 = *(const f32x4*)(xin + (size_t)(pb0 & 0xFFFF) * DIM + d0);
                vb1 = *(const f32x4*)(xin + (size_t)(pb1 & 0xFFFF) * DIM + d0);
                vb2 = *(const f32x4*)(xin + (size_t)(pb2 & 0xFFFF) * DIM + d0);
                vb3 = *(const f32x4*)(xin + (size_t)(pb3 & 0xFFFF) * DIM + d0);
            }
            // consume batch i (gathers issued one iteration ago)
            CONSUME_EDGE(pa0, va0);
            CONSUME_EDGE(pa1, va1);
            CONSUME_EDGE(pa2, va2);
            CONSUME_EDGE(pa3, va3);
            // rotate
            pa0 = pb0; pa1 = pb1; pa2 = pb2; pa3 = pb3;
            pb0 = pc0; pb1 = pc1; pb2 = pc2; pb3 = pc3;
            va0 = vb0; va1 = vb1; va2 = vb2; va3 = vb3;
        }
        // tail (0..3 edges): issue all gathers first, then consume
        {
            const int et = e0 + nb4 * 4;
            const int rem = e1 - et;
            int pt0 = 0, pt1 = 0, pt2 = 0;
            if (rem > 0) pt0 = edges[et];
            if (rem > 1) pt1 = edges[et + 1];
            if (rem > 2) pt2 = edges[et + 2];
            f32x4 vt0, vt1, vt2;
            if (rem > 0) vt0 = *(const f32x4*)(xin + (size_t)(pt0 & 0xFFFF) * DIM + d0);
            if (rem > 1) vt1 = *(const f32x4*)(xin + (size_t)(pt1 & 0xFFFF) * DIM + d0);
            if (rem > 2) vt2 = *(const f32x4*)(xin + (size_t)(pt2 & 0xFFFF) * DIM + d0);
            if (rem > 0) CONSUME_EDGE(pt0, vt0);
            if (rem > 1) CONSUME_EDGE(pt1, vt1);
            if (rem > 2) CONSUME_EDGE(pt2, vt2);
        }
        if (rcur >= 0) FLUSH_FRAG(rcur);
#undef CONSUME_EDGE
#undef FLUSH_FRAG
    }
    __syncthreads();

    // ---- phase 2: MFMA GEMM, each of 8 waves owns one 16-col strip ----
    const int w = tid >> 6;
    const int lane = tid & 63;
    const int q2 = lane >> 4, mm = lane & 15;
    const int a_even = (q2 * 16 + (mm ^ q2)) * 8;        // kt even
    const int a_odd  = (q2 * 16 + ((mm ^ q2) ^ 4)) * 8;  // kt odd (parity swizzle)
    const int n0 = w * 16 + mm;
    const ushort* bph = Whi + n0 * 32 + q2 * 8;
    const ushort* bpl = Wlo + n0 * 32 + q2 * 8;
    floatx4 acc0 = {0.f, 0.f, 0.f, 0.f};
    for (int kt = 0; kt < 32; kt += 2) {
        {
            const short8 ah = *(const short8*)(sHi + kt * 512 + a_even);
            const short8 al = *(const short8*)(sLo + kt * 512 + a_even);
            const short8 bh = *(const short8*)(bph + kt * 4096);
            const short8 bl = *(const short8*)(bpl + kt * 4096);
            acc0 = __builtin_amdgcn_mfma_f32_16x16x32_bf16(ah, bh, acc0, 0, 0, 0);
            acc0 = __builtin_amdgcn_mfma_f32_16x16x32_bf16(ah, bl, acc0, 0, 0, 0);
            acc0 = __builtin_amdgcn_mfma_f32_16x16x32_bf16(al, bh, acc0, 0, 0, 0);
        }
        {
            const int kto = kt + 1;
            const short8 ah = *(const short8*)(sHi + kto * 512 + a_odd);
            const short8 al = *(const short8*)(sLo + kto * 512 + a_odd);
            const short8 bh = *(const short8*)(bph + kto * 4096);
            const short8 bl = *(const short8*)(bpl + kto * 4096);
            acc0 = __builtin_amdgcn_mfma_f32_16x16x32_bf16(ah, bh, acc0, 0, 0, 0);
            acc0 = __builtin_amdgcn_mfma_f32_16x16x32_bf16(ah, bl, acc0, 0, 0, 0);
            acc0 = __builtin_amdgcn_mfma_f32_16x16x32_bf16(al, bh, acc0, 0, 0, 0);
        }
    }
    const float b0 = bias[n0];
    float gp[4];
#pragma unroll
    for (int r = 0; r < 4; r++) {
        const int node = blockIdx.x * NB + q2 * 4 + r;  // C/D: row=(lane>>4)*4+reg, col=lane&15
        float v0 = acc0[r] + b0;
        if (RELU) v0 = fmaxf(v0, 0.f);
        hout[(size_t)node * DIM + n0] = v0;
        if (GATE) gp[r] = v0 * gw[n0];
    }
    if (GATE) {
#pragma unroll
        for (int r = 0; r < 4; r++) {
#pragma unroll
            for (int s = 1; s < 16; s <<= 1) gp[r] += __shfl_xor(gp[r], s, 16);
        }
        if (mm == 0) {
#pragma unroll
            for (int r = 0; r < 4; r++) sgatep[q2 * 4 + r][w] = gp[r];
        }
        __syncthreads();
        if (tid < NB) {
            float s = 0.f;
#pragma unroll
            for (int w8 = 0; w8 < 8; w8++) s += sgatep[tid][w8];
            gate[blockIdx.x * NB + tid] = s + gb[0];
        }
    }
}

// One block (256 threads) per graph: segment softmax + weighted readout + MLP head + sigmoid.
__global__ __launch_bounds__(256) void k_pool(
    const float* __restrict__ h3, const float* __restrict__ gate, const int* __restrict__ n2g,
    const float* __restrict__ fc1w, const float* __restrict__ fc1b,
    const float* __restrict__ fc2w, const float* __restrict__ fc2b,
    const float* __restrict__ fc3w, const float* __restrict__ fc3b,
    float* __restrict__ out, int N) {
    const int g = blockIdx.x;
    const int tid = threadIdx.x;
    __shared__ float sred[256];
    __shared__ float sr[128];
    __shared__ float sz1[100];
    __shared__ float sz2[64];
    __shared__ float sm, ssum;

    const int s = lower_bound_i(n2g, N, g);
    const int e = lower_bound_i(n2g, N, g + 1);

    float m = -3.4e38f;
    for (int n = s + tid; n < e; n += 256) m = fmaxf(m, gate[n]);
    sred[tid] = m;
    __syncthreads();
    for (int off = 128; off > 0; off >>= 1) {
        if (tid < off) sred[tid] = fmaxf(sred[tid], sred[tid + off]);
        __syncthreads();
    }
    if (tid == 0) sm = sred[0];
    __syncthreads();
    const float mm = sm;

    float sum = 0.f;
    for (int n = s + tid; n < e; n += 256) sum += expf(gate[n] - mm);
    sred[tid] = sum;
    __syncthreads();
    for (int off = 128; off > 0; off >>= 1) {
        if (tid < off) sred[tid] += sred[tid + off];
        __syncthreads();
    }
    if (tid == 0) ssum = sred[0];
    __syncthreads();
    const float inv = (e > s) ? 1.0f / ssum : 0.f;

    // weighted readout: col = tid&127, node stream split across two halves
    const int col = tid & 127;
    const int half = tid >> 7;
    float acc = 0.f;
    int n = s + half;
    for (; n + 2 < e; n += 4) {
        const float w0 = expf(gate[n] - mm);
        const float w1 = expf(gate[n + 2] - mm);
        const float a0 = h3[(size_t)n * DIM + col];
        const float a1 = h3[(size_t)(n + 2) * DIM + col];
        acc = fmaf(w0, a0, acc);
        acc = fmaf(w1, a1, acc);
    }
    for (; n < e; n += 2) {
        const float wgt = expf(gate[n] - mm);
        acc = fmaf(wgt, h3[(size_t)n * DIM + col], acc);
    }
    sred[tid] = acc;
    __syncthreads();
    if (tid < 128) sr[tid] = (sred[tid] + sred[tid + 128]) * inv;
    __syncthreads();

    if (tid < 100) {
        float t = fc1b[tid];
        for (int i = 0; i < 128; i++) t = fmaf(sr[i], fc1w[i * 100 + tid], t);
        sz1[tid] = fmaxf(t, 0.f);
    }
    __syncthreads();
    if (tid < 64) {
        float t = fc2b[tid];
        for (int i = 0; i < 100; i++) t = fmaf(sz1[i], fc2w[i * 64 + tid], t);
        sz2[tid] = fmaxf(t, 0.f);
    }
    __syncthreads();
    if (tid < 64) {
        float p = sz2[tid] * fc3w[tid];
#pragma unroll
        for (int off = 32; off > 0; off >>= 1) p += __shfl_down(p, off, 64);
        if (tid == 0) {
            const float z = p + fc3b[0];
            out[g] = 1.0f / (1.0f + expf(-z));
        }
    }
}

extern "C" void kernel_launch(void* const* d_in, const int* in_sizes, int n_in,
                              void* d_out, int out_size, void* d_ws, size_t ws_size,
                              hipStream_t stream) {
    (void)in_sizes; (void)n_in; (void)out_size; (void)ws_size;
    const float* features = (const float*)d_in[0];
    const int*   src      = (const int*)d_in[1];
    const int*   dst      = (const int*)d_in[2];
    const int*   etype    = (const int*)d_in[3];
    const int*   n2g      = (const int*)d_in[4];
    const float* bases1   = (const float*)d_in[5];
    const float* comp1    = (const float*)d_in[6];
    const float* bias1    = (const float*)d_in[7];
    const float* bases2   = (const float*)d_in[8];
    const float* comp2    = (const float*)d_in[9];
    const float* bias2    = (const float*)d_in[10];
    const float* bases3   = (const float*)d_in[11];
    const float* comp3    = (const float*)d_in[12];
    const float* bias3    = (const float*)d_in[13];
    const float* gate_w   = (const float*)d_in[14];
    const float* gate_b   = (const float*)d_in[15];
    const float* fc1w     = (const float*)d_in[16];
    const float* fc1b     = (const float*)d_in[17];
    const float* fc2w     = (const float*)d_in[18];
    const float* fc2b     = (const float*)d_in[19];
    const float* fc3w     = (const float*)d_in[20];
    const float* fc3b     = (const float*)d_in[21];
    float* out = (float*)d_out;

    char* w = (char*)d_ws;
    auto alloc = [&](size_t bytes) -> char* {
        char* p = w;
        w += (bytes + 255) & ~(size_t)255;
        return p;
    };
    int*    offsets = (int*)alloc((NKEY + 1) * sizeof(int));
    int*    edges   = (int*)alloc(N_EDGES * sizeof(int));
    float*  hA      = (float*)alloc((size_t)N_NODES * DIM * sizeof(float));
    float*  hB      = (float*)alloc((size_t)N_NODES * DIM * sizeof(float));
    float*  gate    = (float*)alloc(N_NODES * sizeof(float));
    ushort* Whi1    = (ushort*)alloc((size_t)KDIM * DIM * sizeof(ushort));
    ushort* Wlo1    = (ushort*)alloc((size_t)KDIM * DIM * sizeof(ushort));
    ushort* Whi2    = (ushort*)alloc((size_t)KDIM * DIM * sizeof(ushort));
    ushort* Wlo2    = (ushort*)alloc((size_t)KDIM * DIM * sizeof(ushort));
    ushort* Whi3    = (ushort*)alloc((size_t)KDIM * DIM * sizeof(ushort));
    ushort* Wlo3    = (ushort*)alloc((size_t)KDIM * DIM * sizeof(ushort));
    // CSR scratch aliased into hB (hB is first written in layer 2, after CSR build)
    int*    cursor  = (int*)hB;                              // NSEG2*SEG ints = 1.6 MB
    int*    segscan = (int*)((char*)hB + (2u << 20));        // 1.6 MB at +2 MB
    int*    segtot  = (int*)((char*)hB + (4u << 20));
    int*    segbase = (int*)((char*)hB + (4u << 20) + 4096);

    // weight packing: W_r = comp@bases, bf16 hi/lo, MFMA fragment order
    k_packW<<<(KDIM * DIM) / 256, 256, 0, stream>>>(bases1, comp1, Whi1, Wlo1);
    k_packW<<<(KDIM * DIM) / 256, 256, 0, stream>>>(bases2, comp2, Whi2, Wlo2);
    k_packW<<<(KDIM * DIM) / 256, 256, 0, stream>>>(bases3, comp3, Whi3, Wlo3);

    // (node,rel)-keyed CSR (rebuilt every call)
    hipMemsetAsync(cursor, 0, (size_t)NSEG2 * SEG * sizeof(int), stream);
    k_count<<<(N_EDGES + 255) / 256, 256, 0, stream>>>(dst, etype, cursor, N_EDGES);
    k_scan_seg<<<NSEG2, 256, 0, stream>>>(cursor, segscan, segtot);
    k_scan_tot<<<1, 512, 0, stream>>>(segtot, segbase);
    k_scan_fin<<<(NKEY + 256) / 256, 256, 0, stream>>>(segscan, segbase, offsets, cursor);
    k_fill<<<(N_EDGES + 255) / 256, 256, 0, stream>>>(src, dst, etype, cursor, edges, N_EDGES);

    // 3 RGCN layers (relation-sorted aggregation + fused MFMA GEMM; layer 3 fuses gate)
    k_layer<true, false><<<N_NODES / NB, 512, 0, stream>>>(features, hA, edges, offsets, Whi1, Wlo1, bias1, gate_w, gate_b, gate);
    k_layer<true, false><<<N_NODES / NB, 512, 0, stream>>>(hA, hB, edges, offsets, Whi2, Wlo2, bias2, gate_w, gate_b, gate);
    k_layer<false, true><<<N_NODES / NB, 512, 0, stream>>>(hB, hA, edges, offsets, Whi3, Wlo3, bias3, gate_w, gate_b, gate);

    // pooling + MLP head (gate computed in layer 3)
    k_pool<<<N_GRAPHS, 256, 0, stream>>>(hA, gate, n2g, fc1w, fc1b, fc2w, fc2b, fc3w, fc3b, out, N_NODES);
}

// Round 10
// 532.401 us; speedup vs baseline: 3.1160x; 1.1195x over previous
//
#include <hip/hip_runtime.h>
#include <hip/hip_bf16.h>
#include <math.h>

#define N_NODES 50000
#define N_EDGES 600000
#define DIM 128
#define N_REL 8
#define N_GRAPHS 256
#define NBN 32                // nodes per block (grid 1563; last block half-full)
#define NBLK ((N_NODES + NBN - 1) / NBN)  // 1563
#define KDIM (N_REL * DIM)    // relation-stacked K = 1024
#define NKEY (N_NODES * N_REL)  // 400000 (node,rel) keys
#define SEG 1024
#define NSEG2 391             // ceil(400000/1024); NSEG2*SEG = 400384

typedef __attribute__((ext_vector_type(8))) short short8;
typedef __attribute__((ext_vector_type(4))) float floatx4;
typedef __attribute__((ext_vector_type(4))) float f32x4;
typedef unsigned int uint;
typedef unsigned short ushort;

static __device__ __forceinline__ int lower_bound_i(const int* a, int n, int v) {
    int lo = 0, hi = n;
    while (lo < hi) { int mid = (lo + hi) >> 1; if (a[mid] < v) lo = mid + 1; else hi = mid; }
    return lo;
}

// RNE float->bf16 split: hiword = bf16(x)|bf16(y)<<16 ; loword = bf16(x-hi)|bf16(y-hi)<<16
static __device__ __forceinline__ uint2 split2(float x, float y) {
    uint ux = __float_as_uint(x);
    uint hx = (ux + 0x7FFFu + ((ux >> 16) & 1u)) & 0xFFFF0000u;
    float rx = x - __uint_as_float(hx);
    uint urx = __float_as_uint(rx);
    uint lx = (urx + 0x7FFFu + ((urx >> 16) & 1u)) >> 16;
    uint uy = __float_as_uint(y);
    uint hy = (uy + 0x7FFFu + ((uy >> 16) & 1u)) & 0xFFFF0000u;
    float ry = y - __uint_as_float(hy);
    uint ury = __float_as_uint(ry);
    uint ly = (ury + 0x7FFFu + ((ury >> 16) & 1u)) >> 16;
    return make_uint2((hx >> 16) | (hy & 0xFFFF0000u), lx | (ly << 16));
}

__global__ void k_count(const int* __restrict__ dst, const int* __restrict__ etype,
                        int* __restrict__ counts, int e) {
    int i = blockIdx.x * blockDim.x + threadIdx.x;
    if (i < e) atomicAdd(&counts[dst[i] * 8 + etype[i]], 1);
}

// --- coalesced 3-kernel exclusive scan over counts[NSEG2*SEG] (padding zeroed) ---
__global__ __launch_bounds__(256) void k_scan_seg(const int* __restrict__ counts,
                                                  int* __restrict__ segscan,
                                                  int* __restrict__ segtot) {
    const int b = blockIdx.x, t = threadIdx.x;
    const int base = b * SEG + t * 4;
    const int4 v = *(const int4*)(counts + base);
    const int s0 = v.x, s1 = s0 + v.y, s2 = s1 + v.z, s3 = s2 + v.w;
    __shared__ int sl[256];
    sl[t] = s3;
    __syncthreads();
    for (int off = 1; off < 256; off <<= 1) {
        int add = (t >= off) ? sl[t - off] : 0;
        __syncthreads();
        sl[t] += add;
        __syncthreads();
    }
    const int tp = sl[t] - s3;
    int4 o;
    o.x = tp; o.y = tp + s0; o.z = tp + s1; o.w = tp + s2;
    *(int4*)(segscan + base) = o;
    if (t == 255) segtot[b] = sl[255];
}

__global__ __launch_bounds__(512) void k_scan_tot(const int* __restrict__ segtot,
                                                  int* __restrict__ segbase) {
    const int t = threadIdx.x;  // 512 threads, 1 block
    const int v = (t < NSEG2) ? segtot[t] : 0;
    __shared__ int sl[512];
    sl[t] = v;
    __syncthreads();
    for (int off = 1; off < 512; off <<= 1) {
        int u = (t >= off) ? sl[t - off] : 0;
        __syncthreads();
        sl[t] += u;
        __syncthreads();
    }
    if (t < NSEG2) segbase[t] = sl[t] - v;
    if (t == NSEG2) segbase[NSEG2] = sl[NSEG2 - 1];
}

__global__ void k_scan_fin(const int* __restrict__ segscan, const int* __restrict__ segbase,
                           int* __restrict__ offsets, int* __restrict__ cursor) {
    const int i = blockIdx.x * blockDim.x + threadIdx.x;
    if (i < NKEY) {
        const int val = segbase[i >> 10] + segscan[i];
        offsets[i] = val;
        cursor[i] = val;
    } else if (i == NKEY) {
        offsets[NKEY] = segbase[NSEG2];
    }
}

// scatter edges grouped by (dst, etype); word = src(16b) | etype(3b @16)
__global__ void k_fill(const int* __restrict__ src, const int* __restrict__ dst,
                       const int* __restrict__ etype, int* cursor,
                       int* __restrict__ edges, int e) {
    int i = blockIdx.x * blockDim.x + threadIdx.x;
    if (i < e) {
        const int et = etype[i];
        int pos = atomicAdd(&cursor[dst[i] * 8 + et], 1);
        edges[pos] = src[i] | (et << 16);
    }
}

// W[k=r*128+dk][col] = sum_b comp[r,b]*bases[b][dk][col], packed bf16 hi/lo into
// MFMA-B-fragment order [kt:32][col:128][kk:32] ushort. (Verified R7/R9.)
__global__ void k_packW(const float* __restrict__ bases, const float* __restrict__ comp,
                        ushort* __restrict__ Whi, ushort* __restrict__ Wlo) {
    int id = blockIdx.x * blockDim.x + threadIdx.x;  // 131072
    int nn = id & 127, k = id >> 7;
    int r = k >> 7, dk = k & 127;
    const float* cp = comp + r * 8;
    float v = 0.f;
#pragma unroll
    for (int b = 0; b < 8; b++) v = fmaf(cp[b], bases[((size_t)b * 128 + dk) * 128 + nn], v);
    uint u = __float_as_uint(v);
    uint hu = (u + 0x7FFFu + ((u >> 16) & 1u)) & 0xFFFF0000u;
    float rf = v - __uint_as_float(hu);
    uint ur = __float_as_uint(rf);
    uint lu = (ur + 0x7FFFu + ((ur >> 16) & 1u)) >> 16;
    int kt = k >> 5, kk = k & 31;
    int off = kt * 4096 + nn * 32 + kk;
    Whi[off] = (ushort)(hu >> 16);
    Wlo[off] = (ushort)lu;
}

// One RGCN layer, fused, 512 threads (8 waves), 32 NODES PER BLOCK via
// relation-halved K-processing (edges sorted by (node,rel), so each half's
// edges are contiguous):
//   round h in {0,1}:
//     zero 64KB A-LDS -> aggregate relations h*4..h*4+3 for 32 nodes (one node
//     per half-wave x2 visits, 4 dims/lane, depth-2 gather pipeline, per-edge
//     consume = tmp += v, flush bf16 hi/lo on relation change) -> MFMA kt
//     h*16..h*16+15 accumulating into persistent VGPRs (2 row-tiles/wave).
//   B (relation-stacked W, comp folded) is read ONCE per 32 nodes -> B L2
//   traffic halves vs NB=16. Numerics identical to R9 (3-term split).
//  GATE (layer 3): epilogue via 16-lane shuffle reduce + LDS partials (NO
//  ATOMICS — R7 pitfall).
//
// PITFALL (R3): do NOT scalarize loads of per-call-rebuilt arrays
// (edges/offsets) — compiler s_load via scalar cache serves STALE data on
// graph replay. Keep lane-derived (vector) addressing.
// PITFALL (R7): NO per-lane float atomicAdd on LDS — compiles to CAS loop.
template <bool RELU, bool GATE>
__global__ __launch_bounds__(512, 4) void k_layer(
    const float* __restrict__ xin, float* __restrict__ hout,
    const int* __restrict__ edges, const int* __restrict__ offsets,
    const ushort* __restrict__ Whi, const ushort* __restrict__ Wlo,
    const float* __restrict__ bias,
    const float* __restrict__ gw, const float* __restrict__ gb,
    float* __restrict__ gate) {
    __shared__ ushort sHi[16 * 1024];  // 32 KiB: [kt':16][chunk:128][8]
    __shared__ ushort sLo[16 * 1024];  // 32 KiB
    __shared__ float sgatep[NBN][8];
    const int tid = threadIdx.x;
    const int lane = tid & 63;
    const int w = tid >> 6;
    const int q2 = lane >> 4, mm = lane & 15;
    const int xev = (mm ^ q2) * 8;        // A chunk sub-offset, kt' even
    const int xod = ((mm ^ q2) ^ 4) * 8;  // kt' odd (parity swizzle)
    const int aq = q2 * 256;              // q-group base (ushort)
    const int n0 = w * 16 + mm;
    const ushort* bph = Whi + n0 * 32 + q2 * 8;
    const ushort* bpl = Wlo + n0 * 32 + q2 * 8;
    floatx4 acc0 = {0.f, 0.f, 0.f, 0.f};  // rows 0..15
    floatx4 acc1 = {0.f, 0.f, 0.f, 0.f};  // rows 16..31

    const int hw = tid >> 5, l5 = tid & 31;
    const int d0 = l5 * 4;
    const int kt_off = l5 >> 3;      // 0..3
    const int q = (l5 >> 1) & 3;
    const int jb = (l5 & 1) * 4;

#pragma unroll
    for (int h = 0; h < 2; ++h) {
        // ---- zero A-fragment LDS (empty (node,rel) slots contribute 0) ----
        {
            uint4 z = make_uint4(0u, 0u, 0u, 0u);
#pragma unroll
            for (int i = 0; i < 4; ++i) {
                ((uint4*)sHi)[tid + i * 512] = z;
                ((uint4*)sLo)[tid + i * 512] = z;
            }
        }
        __syncthreads();

        // ---- phase 1: aggregate relations h*4..h*4+3; 2 nodes per half-wave ----
        for (int v = 0; v < 2; ++v) {
            const int m = hw * 2 + v;
            const int n = blockIdx.x * NBN + m;
            int e0 = 0, e1 = 0;
            if (n < N_NODES) { e0 = offsets[n * 8 + h * 4]; e1 = offsets[n * 8 + h * 4 + 4]; }
            f32x4 tmp = (f32x4)0.f;
            int rcur = -1;

#define FLUSH_FRAG(RRR)                                                        \
            {                                                                  \
                const int ktp = (RRR) * 4 + kt_off;                            \
                const int chunk = q * 32 + ((m ^ q) ^ ((ktp & 1) << 2));       \
                const int uoff = ktp * 1024 + chunk * 8 + jb;                  \
                const uint2 p01 = split2(tmp.x, tmp.y);                        \
                const uint2 p23 = split2(tmp.z, tmp.w);                        \
                *(uint2*)(sHi + uoff) = make_uint2(p01.x, p23.x);              \
                *(uint2*)(sLo + uoff) = make_uint2(p01.y, p23.y);              \
            }

#define CONSUME_EDGE(PK, VV)                                                   \
            {                                                                  \
                const int r_ = ((PK) >> 16) & 3;                               \
                if (r_ != rcur) {                                              \
                    if (rcur >= 0) FLUSH_FRAG(rcur);                           \
                    rcur = r_;                                                 \
                    tmp = (VV);                                                \
                } else {                                                       \
                    tmp += (VV);                                               \
                }                                                              \
            }

            const int nb4 = (e1 - e0) >> 2;
            int pa0 = 0, pa1 = 0, pa2 = 0, pa3 = 0;
            int pb0 = 0, pb1 = 0, pb2 = 0, pb3 = 0;
            f32x4 va0, va1, va2, va3;
            if (0 < nb4) { const int ee = e0;     pa0 = edges[ee]; pa1 = edges[ee + 1]; pa2 = edges[ee + 2]; pa3 = edges[ee + 3]; }
            if (1 < nb4) { const int ee = e0 + 4; pb0 = edges[ee]; pb1 = edges[ee + 1]; pb2 = edges[ee + 2]; pb3 = edges[ee + 3]; }
            if (0 < nb4) {
                va0 = *(const f32x4*)(xin + (size_t)(pa0 & 0xFFFF) * DIM + d0);
                va1 = *(const f32x4*)(xin + (size_t)(pa1 & 0xFFFF) * DIM + d0);
                va2 = *(const f32x4*)(xin + (size_t)(pa2 & 0xFFFF) * DIM + d0);
                va3 = *(const f32x4*)(xin + (size_t)(pa3 & 0xFFFF) * DIM + d0);
            }
            for (int i = 0; i < nb4; ++i) {
                int pc0 = 0, pc1 = 0, pc2 = 0, pc3 = 0;
                if (i + 2 < nb4) {
                    const int ee = e0 + (i + 2) * 4;
                    pc0 = edges[ee]; pc1 = edges[ee + 1]; pc2 = edges[ee + 2]; pc3 = edges[ee + 3];
                }
                f32x4 vb0, vb1, vb2, vb3;
                if (i + 1 < nb4) {
                    vb0 = *(const f32x4*)(xin + (size_t)(pb0 & 0xFFFF) * DIM + d0);
                    vb1 = *(const f32x4*)(xin + (size_t)(pb1 & 0xFFFF) * DIM + d0);
                    vb2 = *(const f32x4*)(xin + (size_t)(pb2 & 0xFFFF) * DIM + d0);
                    vb3 = *(const f32x4*)(xin + (size_t)(pb3 & 0xFFFF) * DIM + d0);
                }
                CONSUME_EDGE(pa0, va0);
                CONSUME_EDGE(pa1, va1);
                CONSUME_EDGE(pa2, va2);
                CONSUME_EDGE(pa3, va3);
                pa0 = pb0; pa1 = pb1; pa2 = pb2; pa3 = pb3;
                pb0 = pc0; pb1 = pc1; pb2 = pc2; pb3 = pc3;
                va0 = vb0; va1 = vb1; va2 = vb2; va3 = vb3;
            }
            {
                const int et = e0 + nb4 * 4;
                const int rem = e1 - et;
                int pt0 = 0, pt1 = 0, pt2 = 0;
                if (rem > 0) pt0 = edges[et];
                if (rem > 1) pt1 = edges[et + 1];
                if (rem > 2) pt2 = edges[et + 2];
                f32x4 vt0, vt1, vt2;
                if (rem > 0) vt0 = *(const f32x4*)(xin + (size_t)(pt0 & 0xFFFF) * DIM + d0);
                if (rem > 1) vt1 = *(const f32x4*)(xin + (size_t)(pt1 & 0xFFFF) * DIM + d0);
                if (rem > 2) vt2 = *(const f32x4*)(xin + (size_t)(pt2 & 0xFFFF) * DIM + d0);
                if (rem > 0) CONSUME_EDGE(pt0, vt0);
                if (rem > 1) CONSUME_EDGE(pt1, vt1);
                if (rem > 2) CONSUME_EDGE(pt2, vt2);
            }
            if (rcur >= 0) FLUSH_FRAG(rcur);
#undef CONSUME_EDGE
#undef FLUSH_FRAG
        }
        __syncthreads();

        // ---- phase 2 (this K-half): MFMA, wave owns 16-col strip, 2 row-tiles ----
        for (int kt = 0; kt < 16; kt += 2) {
            {
                const int ktg = h * 16 + kt;
                const ushort* ap = sHi + kt * 1024 + aq;
                const ushort* alp = sLo + kt * 1024 + aq;
                const short8 ah0 = *(const short8*)(ap + xev);
                const short8 ah1 = *(const short8*)(ap + 128 + xev);
                const short8 al0 = *(const short8*)(alp + xev);
                const short8 al1 = *(const short8*)(alp + 128 + xev);
                const short8 bh = *(const short8*)(bph + ktg * 4096);
                const short8 bl = *(const short8*)(bpl + ktg * 4096);
                acc0 = __builtin_amdgcn_mfma_f32_16x16x32_bf16(ah0, bh, acc0, 0, 0, 0);
                acc1 = __builtin_amdgcn_mfma_f32_16x16x32_bf16(ah1, bh, acc1, 0, 0, 0);
                acc0 = __builtin_amdgcn_mfma_f32_16x16x32_bf16(ah0, bl, acc0, 0, 0, 0);
                acc1 = __builtin_amdgcn_mfma_f32_16x16x32_bf16(ah1, bl, acc1, 0, 0, 0);
                acc0 = __builtin_amdgcn_mfma_f32_16x16x32_bf16(al0, bh, acc0, 0, 0, 0);
                acc1 = __builtin_amdgcn_mfma_f32_16x16x32_bf16(al1, bh, acc1, 0, 0, 0);
            }
            {
                const int kto = kt + 1;
                const int ktg = h * 16 + kto;
                const ushort* ap = sHi + kto * 1024 + aq;
                const ushort* alp = sLo + kto * 1024 + aq;
                const short8 ah0 = *(const short8*)(ap + xod);
                const short8 ah1 = *(const short8*)(ap + 128 + xod);
                const short8 al0 = *(const short8*)(alp + xod);
                const short8 al1 = *(const short8*)(alp + 128 + xod);
                const short8 bh = *(const short8*)(bph + ktg * 4096);
                const short8 bl = *(const short8*)(bpl + ktg * 4096);
                acc0 = __builtin_amdgcn_mfma_f32_16x16x32_bf16(ah0, bh, acc0, 0, 0, 0);
                acc1 = __builtin_amdgcn_mfma_f32_16x16x32_bf16(ah1, bh, acc1, 0, 0, 0);
                acc0 = __builtin_amdgcn_mfma_f32_16x16x32_bf16(ah0, bl, acc0, 0, 0, 0);
                acc1 = __builtin_amdgcn_mfma_f32_16x16x32_bf16(ah1, bl, acc1, 0, 0, 0);
                acc0 = __builtin_amdgcn_mfma_f32_16x16x32_bf16(al0, bh, acc0, 0, 0, 0);
                acc1 = __builtin_amdgcn_mfma_f32_16x16x32_bf16(al1, bh, acc1, 0, 0, 0);
            }
        }
        if (h == 0) __syncthreads();  // phase-2 reads done before round-1 zeroing
    }

    // ---- epilogue: bias/relu, store, optional fused gate ----
    const float b0 = bias[n0];
    float gp0[4], gp1[4];
#pragma unroll
    for (int r = 0; r < 4; r++) {
        const int row0 = q2 * 4 + r;            // C/D: row=(lane>>4)*4+reg, col=lane&15
        const int nodeA = blockIdx.x * NBN + row0;
        const int nodeB = nodeA + 16;
        float v0 = acc0[r] + b0;
        float v1 = acc1[r] + b0;
        if (RELU) { v0 = fmaxf(v0, 0.f); v1 = fmaxf(v1, 0.f); }
        if (nodeA < N_NODES) hout[(size_t)nodeA * DIM + n0] = v0;
        if (nodeB < N_NODES) hout[(size_t)nodeB * DIM + n0] = v1;
        if (GATE) { gp0[r] = v0 * gw[n0]; gp1[r] = v1 * gw[n0]; }
    }
    if (GATE) {
#pragma unroll
        for (int r = 0; r < 4; r++) {
#pragma unroll
            for (int s = 1; s < 16; s <<= 1) {
                gp0[r] += __shfl_xor(gp0[r], s, 16);
                gp1[r] += __shfl_xor(gp1[r], s, 16);
            }
        }
        if (mm == 0) {
#pragma unroll
            for (int r = 0; r < 4; r++) {
                sgatep[q2 * 4 + r][w] = gp0[r];
                sgatep[16 + q2 * 4 + r][w] = gp1[r];
            }
        }
        __syncthreads();
        if (tid < NBN) {
            const int n = blockIdx.x * NBN + tid;
            if (n < N_NODES) {
                float s = 0.f;
#pragma unroll
                for (int w8 = 0; w8 < 8; w8++) s += sgatep[tid][w8];
                gate[n] = s + gb[0];
            }
        }
    }
}

// One block (256 threads) per graph: segment softmax + weighted readout + MLP head + sigmoid.
__global__ __launch_bounds__(256) void k_pool(
    const float* __restrict__ h3, const float* __restrict__ gate, const int* __restrict__ n2g,
    const float* __restrict__ fc1w, const float* __restrict__ fc1b,
    const float* __restrict__ fc2w, const float* __restrict__ fc2b,
    const float* __restrict__ fc3w, const float* __restrict__ fc3b,
    float* __restrict__ out, int N) {
    const int g = blockIdx.x;
    const int tid = threadIdx.x;
    __shared__ float sred[256];
    __shared__ float sr[128];
    __shared__ float sz1[100];
    __shared__ float sz2[64];
    __shared__ float sm, ssum;

    const int s = lower_bound_i(n2g, N, g);
    const int e = lower_bound_i(n2g, N, g + 1);

    float m = -3.4e38f;
    for (int n = s + tid; n < e; n += 256) m = fmaxf(m, gate[n]);
    sred[tid] = m;
    __syncthreads();
    for (int off = 128; off > 0; off >>= 1) {
        if (tid < off) sred[tid] = fmaxf(sred[tid], sred[tid + off]);
        __syncthreads();
    }
    if (tid == 0) sm = sred[0];
    __syncthreads();
    const float mm = sm;

    float sum = 0.f;
    for (int n = s + tid; n < e; n += 256) sum += expf(gate[n] - mm);
    sred[tid] = sum;
    __syncthreads();
    for (int off = 128; off > 0; off >>= 1) {
        if (tid < off) sred[tid] += sred[tid + off];
        __syncthreads();
    }
    if (tid == 0) ssum = sred[0];
    __syncthreads();
    const float inv = (e > s) ? 1.0f / ssum : 0.f;

    // weighted readout: col = tid&127, node stream split across two halves
    const int col = tid & 127;
    const int half = tid >> 7;
    float acc = 0.f;
    int n = s + half;
    for (; n + 2 < e; n += 4) {
        const float w0 = expf(gate[n] - mm);
        const float w1 = expf(gate[n + 2] - mm);
        const float a0 = h3[(size_t)n * DIM + col];
        const float a1 = h3[(size_t)(n + 2) * DIM + col];
        acc = fmaf(w0, a0, acc);
        acc = fmaf(w1, a1, acc);
    }
    for (; n < e; n += 2) {
        const float wgt = expf(gate[n] - mm);
        acc = fmaf(wgt, h3[(size_t)n * DIM + col], acc);
    }
    sred[tid] = acc;
    __syncthreads();
    if (tid < 128) sr[tid] = (sred[tid] + sred[tid + 128]) * inv;
    __syncthreads();

    if (tid < 100) {
        float t = fc1b[tid];
        for (int i = 0; i < 128; i++) t = fmaf(sr[i], fc1w[i * 100 + tid], t);
        sz1[tid] = fmaxf(t, 0.f);
    }
    __syncthreads();
    if (tid < 64) {
        float t = fc2b[tid];
        for (int i = 0; i < 100; i++) t = fmaf(sz1[i], fc2w[i * 64 + tid], t);
        sz2[tid] = fmaxf(t, 0.f);
    }
    __syncthreads();
    if (tid < 64) {
        float p = sz2[tid] * fc3w[tid];
#pragma unroll
        for (int off = 32; off > 0; off >>= 1) p += __shfl_down(p, off, 64);
        if (tid == 0) {
            const float z = p + fc3b[0];
            out[g] = 1.0f / (1.0f + expf(-z));
        }
    }
}

extern "C" void kernel_launch(void* const* d_in, const int* in_sizes, int n_in,
                              void* d_out, int out_size, void* d_ws, size_t ws_size,
                              hipStream_t stream) {
    (void)in_sizes; (void)n_in; (void)out_size; (void)ws_size;
    const float* features = (const float*)d_in[0];
    const int*   src      = (const int*)d_in[1];
    const int*   dst      = (const int*)d_in[2];
    const int*   etype    = (const int*)d_in[3];
    const int*   n2g      = (const int*)d_in[4];
    const float* bases1   = (const float*)d_in[5];
    const float* comp1    = (const float*)d_in[6];
    const float* bias1    = (const float*)d_in[7];
    const float* bases2   = (const float*)d_in[8];
    const float* comp2    = (const float*)d_in[9];
    const float* bias2    = (const float*)d_in[10];
    const float* bases3   = (const float*)d_in[11];
    const float* comp3    = (const float*)d_in[12];
    const float* bias3    = (const float*)d_in[13];
    const float* gate_w   = (const float*)d_in[14];
    const float* gate_b   = (const float*)d_in[15];
    const float* fc1w     = (const float*)d_in[16];
    const float* fc1b     = (const float*)d_in[17];
    const float* fc2w     = (const float*)d_in[18];
    const float* fc2b     = (const float*)d_in[19];
    const float* fc3w     = (const float*)d_in[20];
    const float* fc3b     = (const float*)d_in[21];
    float* out = (float*)d_out;

    char* w = (char*)d_ws;
    auto alloc = [&](size_t bytes) -> char* {
        char* p = w;
        w += (bytes + 255) & ~(size_t)255;
        return p;
    };
    int*    offsets = (int*)alloc((NKEY + 1) * sizeof(int));
    int*    edges   = (int*)alloc(N_EDGES * sizeof(int));
    float*  hA      = (float*)alloc((size_t)N_NODES * DIM * sizeof(float));
    float*  hB      = (float*)alloc((size_t)N_NODES * DIM * sizeof(float));
    float*  gate    = (float*)alloc(N_NODES * sizeof(float));
    ushort* Whi1    = (ushort*)alloc((size_t)KDIM * DIM * sizeof(ushort));
    ushort* Wlo1    = (ushort*)alloc((size_t)KDIM * DIM * sizeof(ushort));
    ushort* Whi2    = (ushort*)alloc((size_t)KDIM * DIM * sizeof(ushort));
    ushort* Wlo2    = (ushort*)alloc((size_t)KDIM * DIM * sizeof(ushort));
    ushort* Whi3    = (ushort*)alloc((size_t)KDIM * DIM * sizeof(ushort));
    ushort* Wlo3    = (ushort*)alloc((size_t)KDIM * DIM * sizeof(ushort));
    // CSR scratch aliased into hB (hB is first written in layer 2, after CSR build)
    int*    cursor  = (int*)hB;                              // NSEG2*SEG ints = 1.6 MB
    int*    segscan = (int*)((char*)hB + (2u << 20));        // 1.6 MB at +2 MB
    int*    segtot  = (int*)((char*)hB + (4u << 20));
    int*    segbase = (int*)((char*)hB + (4u << 20) + 4096);

    // weight packing: W_r = comp@bases, bf16 hi/lo, MFMA fragment order
    k_packW<<<(KDIM * DIM) / 256, 256, 0, stream>>>(bases1, comp1, Whi1, Wlo1);
    k_packW<<<(KDIM * DIM) / 256, 256, 0, stream>>>(bases2, comp2, Whi2, Wlo2);
    k_packW<<<(KDIM * DIM) / 256, 256, 0, stream>>>(bases3, comp3, Whi3, Wlo3);

    // (node,rel)-keyed CSR (rebuilt every call)
    hipMemsetAsync(cursor, 0, (size_t)NSEG2 * SEG * sizeof(int), stream);
    k_count<<<(N_EDGES + 255) / 256, 256, 0, stream>>>(dst, etype, cursor, N_EDGES);
    k_scan_seg<<<NSEG2, 256, 0, stream>>>(cursor, segscan, segtot);
    k_scan_tot<<<1, 512, 0, stream>>>(segtot, segbase);
    k_scan_fin<<<(NKEY + 256) / 256, 256, 0, stream>>>(segscan, segbase, offsets, cursor);
    k_fill<<<(N_EDGES + 255) / 256, 256, 0, stream>>>(src, dst, etype, cursor, edges, N_EDGES);

    // 3 RGCN layers (relation-sorted aggregation + K-halved fused MFMA GEMM, 32 nodes/block)
    k_layer<true, false><<<NBLK, 512, 0, stream>>>(features, hA, edges, offsets, Whi1, Wlo1, bias1, gate_w, gate_b, gate);
    k_layer<true, false><<<NBLK, 512, 0, stream>>>(hA, hB, edges, offsets, Whi2, Wlo2, bias2, gate_w, gate_b, gate);
    k_layer<false, true><<<NBLK, 512, 0, stream>>>(hB, hA, edges, offsets, Whi3, Wlo3, bias3, gate_w, gate_b, gate);

    // pooling + MLP head (gate computed in layer 3)
    k_pool<<<N_GRAPHS, 256, 0, stream>>>(hA, gate, n2g, fc1w, fc1b, fc2w, fc2b, fc3w, fc3b, out, N_NODES);
}

// Round 11
// 460.365 us; speedup vs baseline: 3.6036x; 1.1565x over previous
//
#include <hip/hip_runtime.h>
#include <hip/hip_bf16.h>
#include <math.h>

#define N_NODES 50000
#define N_EDGES 600000
#define DIM 128
#define N_REL 8
#define N_GRAPHS 256
#define NBN 32                // nodes per block (grid 1563; last block half-full)
#define NBLK ((N_NODES + NBN - 1) / NBN)  // 1563
#define KDIM (N_REL * DIM)    // relation-stacked K = 1024
#define NKEY (N_NODES * N_REL)  // 400000 (node,rel) keys
#define SEG 1024
#define NSEG2 391             // ceil(400000/1024); NSEG2*SEG = 400384

typedef __attribute__((ext_vector_type(8))) short short8;
typedef __attribute__((ext_vector_type(4))) float floatx4;
typedef __attribute__((ext_vector_type(4))) float f32x4;
typedef unsigned int uint;
typedef unsigned short ushort;

static __device__ __forceinline__ int lower_bound_i(const int* a, int n, int v) {
    int lo = 0, hi = n;
    while (lo < hi) { int mid = (lo + hi) >> 1; if (a[mid] < v) lo = mid + 1; else hi = mid; }
    return lo;
}

// RNE float->bf16 split: hiword = bf16(x)|bf16(y)<<16 ; loword = bf16(x-hi)|bf16(y-hi)<<16
static __device__ __forceinline__ uint2 split2(float x, float y) {
    uint ux = __float_as_uint(x);
    uint hx = (ux + 0x7FFFu + ((ux >> 16) & 1u)) & 0xFFFF0000u;
    float rx = x - __uint_as_float(hx);
    uint urx = __float_as_uint(rx);
    uint lx = (urx + 0x7FFFu + ((urx >> 16) & 1u)) >> 16;
    uint uy = __float_as_uint(y);
    uint hy = (uy + 0x7FFFu + ((uy >> 16) & 1u)) & 0xFFFF0000u;
    float ry = y - __uint_as_float(hy);
    uint ury = __float_as_uint(ry);
    uint ly = (ury + 0x7FFFu + ((ury >> 16) & 1u)) >> 16;
    return make_uint2((hx >> 16) | (hy & 0xFFFF0000u), lx | (ly << 16));
}

__global__ void k_count(const int* __restrict__ dst, const int* __restrict__ etype,
                        int* __restrict__ counts, int e) {
    int i = blockIdx.x * blockDim.x + threadIdx.x;
    if (i < e) atomicAdd(&counts[dst[i] * 8 + etype[i]], 1);
}

// --- coalesced 3-kernel exclusive scan over counts[NSEG2*SEG] (padding zeroed) ---
__global__ __launch_bounds__(256) void k_scan_seg(const int* __restrict__ counts,
                                                  int* __restrict__ segscan,
                                                  int* __restrict__ segtot) {
    const int b = blockIdx.x, t = threadIdx.x;
    const int base = b * SEG + t * 4;
    const int4 v = *(const int4*)(counts + base);
    const int s0 = v.x, s1 = s0 + v.y, s2 = s1 + v.z, s3 = s2 + v.w;
    __shared__ int sl[256];
    sl[t] = s3;
    __syncthreads();
    for (int off = 1; off < 256; off <<= 1) {
        int add = (t >= off) ? sl[t - off] : 0;
        __syncthreads();
        sl[t] += add;
        __syncthreads();
    }
    const int tp = sl[t] - s3;
    int4 o;
    o.x = tp; o.y = tp + s0; o.z = tp + s1; o.w = tp + s2;
    *(int4*)(segscan + base) = o;
    if (t == 255) segtot[b] = sl[255];
}

__global__ __launch_bounds__(512) void k_scan_tot(const int* __restrict__ segtot,
                                                  int* __restrict__ segbase) {
    const int t = threadIdx.x;  // 512 threads, 1 block
    const int v = (t < NSEG2) ? segtot[t] : 0;
    __shared__ int sl[512];
    sl[t] = v;
    __syncthreads();
    for (int off = 1; off < 512; off <<= 1) {
        int u = (t >= off) ? sl[t - off] : 0;
        __syncthreads();
        sl[t] += u;
        __syncthreads();
    }
    if (t < NSEG2) segbase[t] = sl[t] - v;
    if (t == NSEG2) segbase[NSEG2] = sl[NSEG2 - 1];
}

__global__ void k_scan_fin(const int* __restrict__ segscan, const int* __restrict__ segbase,
                           int* __restrict__ offsets, int* __restrict__ cursor) {
    const int i = blockIdx.x * blockDim.x + threadIdx.x;
    if (i < NKEY) {
        const int val = segbase[i >> 10] + segscan[i];
        offsets[i] = val;
        cursor[i] = val;
    } else if (i == NKEY) {
        offsets[NKEY] = segbase[NSEG2];
    }
}

// scatter edges grouped by (dst, etype); word = src(16b) | etype(3b @16)
__global__ void k_fill(const int* __restrict__ src, const int* __restrict__ dst,
                       const int* __restrict__ etype, int* cursor,
                       int* __restrict__ edges, int e) {
    int i = blockIdx.x * blockDim.x + threadIdx.x;
    if (i < e) {
        const int et = etype[i];
        int pos = atomicAdd(&cursor[dst[i] * 8 + et], 1);
        edges[pos] = src[i] | (et << 16);
    }
}

// W[k=r*128+dk][col] = sum_b comp[r,b]*bases[b][dk][col], packed bf16 hi/lo into
// MFMA-B-fragment order [kt:32][col:128][kk:32] ushort. All 3 layers, 1 launch.
__global__ void k_packW3(const float* __restrict__ b1, const float* __restrict__ c1,
                         ushort* __restrict__ Whi1, ushort* __restrict__ Wlo1,
                         const float* __restrict__ b2, const float* __restrict__ c2,
                         ushort* __restrict__ Whi2, ushort* __restrict__ Wlo2,
                         const float* __restrict__ b3, const float* __restrict__ c3,
                         ushort* __restrict__ Whi3, ushort* __restrict__ Wlo3) {
    const int lay = blockIdx.x >> 9;  // 512 blocks per layer
    const int id = (blockIdx.x & 511) * blockDim.x + threadIdx.x;  // 0..131071
    const float* bases = (lay == 0) ? b1 : (lay == 1) ? b2 : b3;
    const float* comp  = (lay == 0) ? c1 : (lay == 1) ? c2 : c3;
    ushort* Whi = (lay == 0) ? Whi1 : (lay == 1) ? Whi2 : Whi3;
    ushort* Wlo = (lay == 0) ? Wlo1 : (lay == 1) ? Wlo2 : Wlo3;
    int nn = id & 127, k = id >> 7;
    int r = k >> 7, dk = k & 127;
    const float* cp = comp + r * 8;
    float v = 0.f;
#pragma unroll
    for (int b = 0; b < 8; b++) v = fmaf(cp[b], bases[((size_t)b * 128 + dk) * 128 + nn], v);
    uint u = __float_as_uint(v);
    uint hu = (u + 0x7FFFu + ((u >> 16) & 1u)) & 0xFFFF0000u;
    float rf = v - __uint_as_float(hu);
    uint ur = __float_as_uint(rf);
    uint lu = (ur + 0x7FFFu + ((ur >> 16) & 1u)) >> 16;
    int kt = k >> 5, kk = k & 31;
    int off = kt * 4096 + nn * 32 + kk;
    Whi[off] = (ushort)(hu >> 16);
    Wlo[off] = (ushort)lu;
}

// One RGCN layer, fused, 512 threads (8 waves), 32 nodes/block, FOUR K-rounds
// (one relation PAIR per round, 33 KB LDS -> 4 blocks/CU):
//   round ro: aggregate rels {2ro, 2ro+1} per node into 2 register accs
//   (branch on rel parity bit — uniform per half-wave), flush BOTH rels
//   unconditionally at visit end (covers every LDS slot -> no zero phase);
//   then MFMA kt ro*8..ro*8+7 accumulating into persistent VGPRs.
//   B (relation-stacked W, comp folded) read once per 32 nodes.
//  GATE (layer 3): epilogue via 16-lane shuffle reduce + LDS partials (NO
//  ATOMICS — R7 pitfall).
//
// PITFALL (R3): do NOT scalarize loads of per-call-rebuilt arrays
// (edges/offsets) — compiler s_load via scalar cache serves STALE data on
// graph replay. Keep lane-derived (vector) addressing.
// PITFALL (R7): NO per-lane float atomicAdd on LDS — compiles to CAS loop.
template <bool RELU, bool GATE>
__global__ __launch_bounds__(512, 8) void k_layer(
    const float* __restrict__ xin, float* __restrict__ hout,
    const int* __restrict__ edges, const int* __restrict__ offsets,
    const ushort* __restrict__ Whi, const ushort* __restrict__ Wlo,
    const float* __restrict__ bias,
    const float* __restrict__ gw, const float* __restrict__ gb,
    float* __restrict__ gate) {
    __shared__ ushort sHi[8 * 1024];  // 16 KiB: [ktp:8][chunk:128][8]
    __shared__ ushort sLo[8 * 1024];  // 16 KiB
    __shared__ float sgatep[NBN][8];
    const int tid = threadIdx.x;
    const int lane = tid & 63;
    const int w = tid >> 6;
    const int q2 = lane >> 4, mm = lane & 15;
    const int xev = (mm ^ q2) * 8;        // A chunk sub-offset, kt even
    const int xod = ((mm ^ q2) ^ 4) * 8;  // kt odd (parity swizzle)
    const int aq = q2 * 256;              // q-group base (ushort)
    const int n0 = w * 16 + mm;
    const ushort* bph = Whi + n0 * 32 + q2 * 8;
    const ushort* bpl = Wlo + n0 * 32 + q2 * 8;
    floatx4 acc0 = {0.f, 0.f, 0.f, 0.f};  // rows 0..15
    floatx4 acc1 = {0.f, 0.f, 0.f, 0.f};  // rows 16..31

    const int hw = tid >> 5, l5 = tid & 31;
    const int d0 = l5 * 4;
    const int kt_off = l5 >> 3;      // 0..3
    const int q = (l5 >> 1) & 3;
    const int jb = (l5 & 1) * 4;

    for (int ro = 0; ro < 4; ++ro) {
        // ---- phase 1: aggregate rel pair {2ro,2ro+1}; 2 nodes per half-wave ----
        for (int v = 0; v < 2; ++v) {
            const int m = hw * 2 + v;
            const int n = blockIdx.x * NBN + m;
            int e = 0, e1 = 0;
            if (n < N_NODES) { e = offsets[n * 8 + ro * 2]; e1 = offsets[n * 8 + ro * 2 + 2]; }
            f32x4 a0 = (f32x4)0.f, a1 = (f32x4)0.f;
            while (e < e1) {
                const int c = e1 - e;
                const int p0 = edges[e];
                const int p1 = (c > 1) ? edges[e + 1] : 0;
                const int p2 = (c > 2) ? edges[e + 2] : 0;
                const int p3 = (c > 3) ? edges[e + 3] : 0;
                f32x4 v0, v1, v2, v3;
                v0 = *(const f32x4*)(xin + (size_t)(p0 & 0xFFFF) * DIM + d0);
                if (c > 1) v1 = *(const f32x4*)(xin + (size_t)(p1 & 0xFFFF) * DIM + d0);
                if (c > 2) v2 = *(const f32x4*)(xin + (size_t)(p2 & 0xFFFF) * DIM + d0);
                if (c > 3) v3 = *(const f32x4*)(xin + (size_t)(p3 & 0xFFFF) * DIM + d0);
                if (p0 & 0x10000) a1 += v0; else a0 += v0;
                if (c > 1) { if (p1 & 0x10000) a1 += v1; else a0 += v1; }
                if (c > 2) { if (p2 & 0x10000) a1 += v2; else a0 += v2; }
                if (c > 3) { if (p3 & 0x10000) a1 += v3; else a0 += v3; }
                e += 4;
            }
            // unconditional flush of both rels (full slot coverage -> no zeroing)
            {
                const int ktp0 = kt_off;                 // even rel -> ktp 0..3
                const int ch0 = q * 32 + ((m ^ q) ^ ((ktp0 & 1) << 2));
                const int u0 = ktp0 * 1024 + ch0 * 8 + jb;
                const uint2 h01 = split2(a0.x, a0.y);
                const uint2 h23 = split2(a0.z, a0.w);
                *(uint2*)(sHi + u0) = make_uint2(h01.x, h23.x);
                *(uint2*)(sLo + u0) = make_uint2(h01.y, h23.y);
                const int ktp1 = 4 + kt_off;             // odd rel -> ktp 4..7
                const int ch1 = q * 32 + ((m ^ q) ^ ((ktp1 & 1) << 2));
                const int u1 = ktp1 * 1024 + ch1 * 8 + jb;
                const uint2 g01 = split2(a1.x, a1.y);
                const uint2 g23 = split2(a1.z, a1.w);
                *(uint2*)(sHi + u1) = make_uint2(g01.x, g23.x);
                *(uint2*)(sLo + u1) = make_uint2(g01.y, g23.y);
            }
        }
        __syncthreads();

        // ---- phase 2 (this K-quarter): MFMA, wave owns 16-col strip, 2 row-tiles ----
        for (int kt = 0; kt < 8; kt += 2) {
            {
                const int ktg = ro * 8 + kt;
                const ushort* ap = sHi + kt * 1024 + aq;
                const ushort* alp = sLo + kt * 1024 + aq;
                const short8 ah0 = *(const short8*)(ap + xev);
                const short8 ah1 = *(const short8*)(ap + 128 + xev);
                const short8 al0 = *(const short8*)(alp + xev);
                const short8 al1 = *(const short8*)(alp + 128 + xev);
                const short8 bh = *(const short8*)(bph + ktg * 4096);
                const short8 bl = *(const short8*)(bpl + ktg * 4096);
                acc0 = __builtin_amdgcn_mfma_f32_16x16x32_bf16(ah0, bh, acc0, 0, 0, 0);
                acc1 = __builtin_amdgcn_mfma_f32_16x16x32_bf16(ah1, bh, acc1, 0, 0, 0);
                acc0 = __builtin_amdgcn_mfma_f32_16x16x32_bf16(ah0, bl, acc0, 0, 0, 0);
                acc1 = __builtin_amdgcn_mfma_f32_16x16x32_bf16(ah1, bl, acc1, 0, 0, 0);
                acc0 = __builtin_amdgcn_mfma_f32_16x16x32_bf16(al0, bh, acc0, 0, 0, 0);
                acc1 = __builtin_amdgcn_mfma_f32_16x16x32_bf16(al1, bh, acc1, 0, 0, 0);
            }
            {
                const int kto = kt + 1;
                const int ktg = ro * 8 + kto;
                const ushort* ap = sHi + kto * 1024 + aq;
                const ushort* alp = sLo + kto * 1024 + aq;
                const short8 ah0 = *(const short8*)(ap + xod);
                const short8 ah1 = *(const short8*)(ap + 128 + xod);
                const short8 al0 = *(const short8*)(alp + xod);
                const short8 al1 = *(const short8*)(alp + 128 + xod);
                const short8 bh = *(const short8*)(bph + ktg * 4096);
                const short8 bl = *(const short8*)(bpl + ktg * 4096);
                acc0 = __builtin_amdgcn_mfma_f32_16x16x32_bf16(ah0, bh, acc0, 0, 0, 0);
                acc1 = __builtin_amdgcn_mfma_f32_16x16x32_bf16(ah1, bh, acc1, 0, 0, 0);
                acc0 = __builtin_amdgcn_mfma_f32_16x16x32_bf16(ah0, bl, acc0, 0, 0, 0);
                acc1 = __builtin_amdgcn_mfma_f32_16x16x32_bf16(ah1, bl, acc1, 0, 0, 0);
                acc0 = __builtin_amdgcn_mfma_f32_16x16x32_bf16(al0, bh, acc0, 0, 0, 0);
                acc1 = __builtin_amdgcn_mfma_f32_16x16x32_bf16(al1, bh, acc1, 0, 0, 0);
            }
        }
        if (ro < 3) __syncthreads();  // phase-2 reads done before next round's flush
    }

    // ---- epilogue: bias/relu, store, optional fused gate ----
    const float b0 = bias[n0];
    float gp0[4], gp1[4];
#pragma unroll
    for (int r = 0; r < 4; r++) {
        const int row0 = q2 * 4 + r;            // C/D: row=(lane>>4)*4+reg, col=lane&15
        const int nodeA = blockIdx.x * NBN + row0;
        const int nodeB = nodeA + 16;
        float v0 = acc0[r] + b0;
        float v1 = acc1[r] + b0;
        if (RELU) { v0 = fmaxf(v0, 0.f); v1 = fmaxf(v1, 0.f); }
        if (nodeA < N_NODES) hout[(size_t)nodeA * DIM + n0] = v0;
        if (nodeB < N_NODES) hout[(size_t)nodeB * DIM + n0] = v1;
        if (GATE) { gp0[r] = v0 * gw[n0]; gp1[r] = v1 * gw[n0]; }
    }
    if (GATE) {
#pragma unroll
        for (int r = 0; r < 4; r++) {
#pragma unroll
            for (int s = 1; s < 16; s <<= 1) {
                gp0[r] += __shfl_xor(gp0[r], s, 16);
                gp1[r] += __shfl_xor(gp1[r], s, 16);
            }
        }
        __syncthreads();  // all phase-2 LDS reads done (paranoia; sgatep separate)
        if (mm == 0) {
#pragma unroll
            for (int r = 0; r < 4; r++) {
                sgatep[q2 * 4 + r][w] = gp0[r];
                sgatep[16 + q2 * 4 + r][w] = gp1[r];
            }
        }
        __syncthreads();
        if (tid < NBN) {
            const int n = blockIdx.x * NBN + tid;
            if (n < N_NODES) {
                float s = 0.f;
#pragma unroll
                for (int w8 = 0; w8 < 8; w8++) s += sgatep[tid][w8];
                gate[n] = s + gb[0];
            }
        }
    }
}

// One block (256 threads) per graph: segment softmax + weighted readout + MLP head + sigmoid.
__global__ __launch_bounds__(256) void k_pool(
    const float* __restrict__ h3, const float* __restrict__ gate, const int* __restrict__ n2g,
    const float* __restrict__ fc1w, const float* __restrict__ fc1b,
    const float* __restrict__ fc2w, const float* __restrict__ fc2b,
    const float* __restrict__ fc3w, const float* __restrict__ fc3b,
    float* __restrict__ out, int N) {
    const int g = blockIdx.x;
    const int tid = threadIdx.x;
    __shared__ float sred[256];
    __shared__ float sr[128];
    __shared__ float sz1[100];
    __shared__ float sz2[64];
    __shared__ float sm, ssum;

    const int s = lower_bound_i(n2g, N, g);
    const int e = lower_bound_i(n2g, N, g + 1);

    float m = -3.4e38f;
    for (int n = s + tid; n < e; n += 256) m = fmaxf(m, gate[n]);
    sred[tid] = m;
    __syncthreads();
    for (int off = 128; off > 0; off >>= 1) {
        if (tid < off) sred[tid] = fmaxf(sred[tid], sred[tid + off]);
        __syncthreads();
    }
    if (tid == 0) sm = sred[0];
    __syncthreads();
    const float mm = sm;

    float sum = 0.f;
    for (int n = s + tid; n < e; n += 256) sum += expf(gate[n] - mm);
    sred[tid] = sum;
    __syncthreads();
    for (int off = 128; off > 0; off >>= 1) {
        if (tid < off) sred[tid] += sred[tid + off];
        __syncthreads();
    }
    if (tid == 0) ssum = sred[0];
    __syncthreads();
    const float inv = (e > s) ? 1.0f / ssum : 0.f;

    // weighted readout: col = tid&127, node stream split across two halves,
    // unrolled x4 per half (8 loads in flight across the block)
    const int col = tid & 127;
    const int half = tid >> 7;
    float acc = 0.f;
    int n = s + half;
    for (; n + 6 < e; n += 8) {
        const float w0 = expf(gate[n] - mm);
        const float w1 = expf(gate[n + 2] - mm);
        const float w2 = expf(gate[n + 4] - mm);
        const float w3 = expf(gate[n + 6] - mm);
        const float a0 = h3[(size_t)n * DIM + col];
        const float a1 = h3[(size_t)(n + 2) * DIM + col];
        const float a2 = h3[(size_t)(n + 4) * DIM + col];
        const float a3 = h3[(size_t)(n + 6) * DIM + col];
        acc = fmaf(w0, a0, acc);
        acc = fmaf(w1, a1, acc);
        acc = fmaf(w2, a2, acc);
        acc = fmaf(w3, a3, acc);
    }
    for (; n < e; n += 2) {
        const float wgt = expf(gate[n] - mm);
        acc = fmaf(wgt, h3[(size_t)n * DIM + col], acc);
    }
    sred[tid] = acc;
    __syncthreads();
    if (tid < 128) sr[tid] = (sred[tid] + sred[tid + 128]) * inv;
    __syncthreads();

    if (tid < 100) {
        float t = fc1b[tid];
        for (int i = 0; i < 128; i++) t = fmaf(sr[i], fc1w[i * 100 + tid], t);
        sz1[tid] = fmaxf(t, 0.f);
    }
    __syncthreads();
    if (tid < 64) {
        float t = fc2b[tid];
        for (int i = 0; i < 100; i++) t = fmaf(sz1[i], fc2w[i * 64 + tid], t);
        sz2[tid] = fmaxf(t, 0.f);
    }
    __syncthreads();
    if (tid < 64) {
        float p = sz2[tid] * fc3w[tid];
#pragma unroll
        for (int off = 32; off > 0; off >>= 1) p += __shfl_down(p, off, 64);
        if (tid == 0) {
            const float z = p + fc3b[0];
            out[g] = 1.0f / (1.0f + expf(-z));
        }
    }
}

extern "C" void kernel_launch(void* const* d_in, const int* in_sizes, int n_in,
                              void* d_out, int out_size, void* d_ws, size_t ws_size,
                              hipStream_t stream) {
    (void)in_sizes; (void)n_in; (void)out_size; (void)ws_size;
    const float* features = (const float*)d_in[0];
    const int*   src      = (const int*)d_in[1];
    const int*   dst      = (const int*)d_in[2];
    const int*   etype    = (const int*)d_in[3];
    const int*   n2g      = (const int*)d_in[4];
    const float* bases1   = (const float*)d_in[5];
    const float* comp1    = (const float*)d_in[6];
    const float* bias1    = (const float*)d_in[7];
    const float* bases2   = (const float*)d_in[8];
    const float* comp2    = (const float*)d_in[9];
    const float* bias2    = (const float*)d_in[10];
    const float* bases3   = (const float*)d_in[11];
    const float* comp3    = (const float*)d_in[12];
    const float* bias3    = (const float*)d_in[13];
    const float* gate_w   = (const float*)d_in[14];
    const float* gate_b   = (const float*)d_in[15];
    const float* fc1w     = (const float*)d_in[16];
    const float* fc1b     = (const float*)d_in[17];
    const float* fc2w     = (const float*)d_in[18];
    const float* fc2b     = (const float*)d_in[19];
    const float* fc3w     = (const float*)d_in[20];
    const float* fc3b     = (const float*)d_in[21];
    float* out = (float*)d_out;

    char* w = (char*)d_ws;
    auto alloc = [&](size_t bytes) -> char* {
        char* p = w;
        w += (bytes + 255) & ~(size_t)255;
        return p;
    };
    int*    offsets = (int*)alloc((NKEY + 1) * sizeof(int));
    int*    edges   = (int*)alloc((N_EDGES + 16) * sizeof(int));
    float*  hA      = (float*)alloc((size_t)N_NODES * DIM * sizeof(float));
    float*  hB      = (float*)alloc((size_t)N_NODES * DIM * sizeof(float));
    float*  gate    = (float*)alloc(N_NODES * sizeof(float));
    ushort* Whi1    = (ushort*)alloc((size_t)KDIM * DIM * sizeof(ushort));
    ushort* Wlo1    = (ushort*)alloc((size_t)KDIM * DIM * sizeof(ushort));
    ushort* Whi2    = (ushort*)alloc((size_t)KDIM * DIM * sizeof(ushort));
    ushort* Wlo2    = (ushort*)alloc((size_t)KDIM * DIM * sizeof(ushort));
    ushort* Whi3    = (ushort*)alloc((size_t)KDIM * DIM * sizeof(ushort));
    ushort* Wlo3    = (ushort*)alloc((size_t)KDIM * DIM * sizeof(ushort));
    // CSR scratch aliased into hB (hB is first written in layer 2, after CSR build)
    int*    cursor  = (int*)hB;                              // NSEG2*SEG ints = 1.6 MB
    int*    segscan = (int*)((char*)hB + (2u << 20));        // 1.6 MB at +2 MB
    int*    segtot  = (int*)((char*)hB + (4u << 20));
    int*    segbase = (int*)((char*)hB + (4u << 20) + 4096);

    // weight packing: W_r = comp@bases, bf16 hi/lo, MFMA fragment order (1 launch)
    k_packW3<<<1536, 256, 0, stream>>>(bases1, comp1, Whi1, Wlo1,
                                       bases2, comp2, Whi2, Wlo2,
                                       bases3, comp3, Whi3, Wlo3);

    // (node,rel)-keyed CSR (rebuilt every call)
    hipMemsetAsync(cursor, 0, (size_t)NSEG2 * SEG * sizeof(int), stream);
    k_count<<<(N_EDGES + 255) / 256, 256, 0, stream>>>(dst, etype, cursor, N_EDGES);
    k_scan_seg<<<NSEG2, 256, 0, stream>>>(cursor, segscan, segtot);
    k_scan_tot<<<1, 512, 0, stream>>>(segtot, segbase);
    k_scan_fin<<<(NKEY + 256) / 256, 256, 0, stream>>>(segscan, segbase, offsets, cursor);
    k_fill<<<(N_EDGES + 255) / 256, 256, 0, stream>>>(src, dst, etype, cursor, edges, N_EDGES);

    // 3 RGCN layers (relation-sorted aggregation + 4-round K-quartered MFMA GEMM)
    k_layer<true, false><<<NBLK, 512, 0, stream>>>(features, hA, edges, offsets, Whi1, Wlo1, bias1, gate_w, gate_b, gate);
    k_layer<true, false><<<NBLK, 512, 0, stream>>>(hA, hB, edges, offsets, Whi2, Wlo2, bias2, gate_w, gate_b, gate);
    k_layer<false, true><<<NBLK, 512, 0, stream>>>(hB, hA, edges, offsets, Whi3, Wlo3, bias3, gate_w, gate_b, gate);

    // pooling + MLP head (gate computed in layer 3)
    k_pool<<<N_GRAPHS, 256, 0, stream>>>(hA, gate, n2g, fc1w, fc1b, fc2w, fc2b, fc3w, fc3b, out, N_NODES);
}